// Round 3
// baseline (486.144 us; speedup 1.0000x reference)
//
#include <hip/hip_runtime.h>

#define VN 5023
#define KN 8
#define BN 64
#define CIN 3
#define CH 64
#define MN 9
#define LAT 128
#define KTOT (VN*CH)      // 321472
#define NBV (BN*VN)       // 321472
#define KC 256
#define NCHUNK 1256       // ceil(KTOT/KC); last chunk has 192 = 6*32 valid k
#define RED_G 8
#define RED_J 157         // 1256 = 8*157 exactly

// ---------------- kernel 1: conv1 (x[B,V,3] -> h[B,V,64], relu) --------------
__global__ __launch_bounds__(256, 4) void k_conv1(
    const float* __restrict__ x, const float* __restrict__ aw,
    const int* __restrict__ dst,
    const float* __restrict__ u_e, const float* __restrict__ c_e,
    const float* __restrict__ W_e, const float* __restrict__ b_e,
    float* __restrict__ h)
{
  int t = blockIdx.x*256 + threadIdx.x;
  if (t >= NBV) return;
  int b = t / VN, v = t - b*VN;
  const float* xb = x + (size_t)b*VN*CIN;
  float xi0 = xb[v*3+0], xi1 = xb[v*3+1], xi2 = xb[v*3+2];
  float Ti[MN];
#pragma unroll
  for (int m=0;m<MN;m++)
    Ti[m] = xi0*u_e[m] + xi1*u_e[MN+m] + xi2*u_e[2*MN+m] + c_e[m];
  float agg[27];
#pragma unroll
  for (int i=0;i<27;i++) agg[i]=0.f;
  for (int k=0;k<KN;k++){
    int e = v*KN+k;
    int j = dst[e];
    float awe = aw[e];
    float xj0 = xb[j*3+0], xj1 = xb[j*3+1], xj2 = xb[j*3+2];
    float lg[MN];
#pragma unroll
    for (int m=0;m<MN;m++)
      lg[m] = Ti[m] - (xj0*u_e[m]+xj1*u_e[MN+m]+xj2*u_e[2*MN+m]);
    float mx = lg[0];
#pragma unroll
    for (int m=1;m<MN;m++) mx = fmaxf(mx, lg[m]);
    float ex[MN], s=0.f;
#pragma unroll
    for (int m=0;m<MN;m++){ ex[m] = __expf(lg[m]-mx); s += ex[m]; }
    float r = awe / s;
#pragma unroll
    for (int m=0;m<MN;m++){
      float a = ex[m]*r;
      agg[m*3+0] += a*xj0; agg[m*3+1] += a*xj1; agg[m*3+2] += a*xj2;
    }
  }
  float* hr = h + (size_t)t*CH;
  // chunked output transform: only 16 accumulators live at a time (no spill)
  for (int cc=0; cc<4; cc++){
    float y[16];
#pragma unroll
    for (int c=0;c<16;c++) y[c] = b_e[cc*16+c];
#pragma unroll
    for (int mc=0; mc<27; mc++){
      float a = agg[mc];
#pragma unroll
      for (int c=0;c<16;c++) y[c] += a * W_e[mc*CH + cc*16 + c];
    }
#pragma unroll
    for (int c=0;c<16;c+=4){
      float4 o = make_float4(fmaxf(y[c],0.f),fmaxf(y[c+1],0.f),
                             fmaxf(y[c+2],0.f),fmaxf(y[c+3],0.f));
      *(float4*)(hr + cc*16 + c) = o;
    }
  }
}

// ---------------- kernel 2: encoder split-K partials -------------------------
// partial[blk][b][l] = sum_{k in chunk} h[b][k] * W_enc[k][l]
// 256 threads: thread (lq=t&15, bq=t>>4) owns 8 l x 4 b -> 32 acc.
// z from LDS (broadcast, conflict-free); w from global (L1/L2), unroll-4
// keeps 8 independent loads in flight per wave. ~19.6 waves/CU.
__global__ __launch_bounds__(256, 4) void k_enc(
    const float* __restrict__ h, const float* __restrict__ We,
    float* __restrict__ partial)
{
  __shared__ float sht[32][72];     // [k-within-32][b], pad 72
  int t = threadIdx.x;
  int blk = blockIdx.x;
  int lq = t & 15;                  // l = lq*8 .. +7
  int bq = t >> 4;                  // b = bq*4 .. +3
  float acc[8][4];
#pragma unroll
  for (int i=0;i<8;i++)
#pragma unroll
    for (int j=0;j<4;j++) acc[i][j]=0.f;
  int kbase0 = blk*KC;
  int ldb = t & 63;                 // staging b row
  int seg = t >> 6;                 // staging k-octet: k = seg*8 .. +7
  int nt0 = (blk == NCHUNK-1) ? 6 : 8;   // last chunk: 192 valid k (uniform)
  for (int t0=0; t0<nt0; t0++){
    int kbase = kbase0 + t0*32;
    __syncthreads();
    float4 v0 = *(const float4*)(h + (size_t)ldb*KTOT + kbase + seg*8);
    float4 v1 = *(const float4*)(h + (size_t)ldb*KTOT + kbase + seg*8 + 4);
    sht[seg*8+0][ldb]=v0.x; sht[seg*8+1][ldb]=v0.y;
    sht[seg*8+2][ldb]=v0.z; sht[seg*8+3][ldb]=v0.w;
    sht[seg*8+4][ldb]=v1.x; sht[seg*8+5][ldb]=v1.y;
    sht[seg*8+6][ldb]=v1.z; sht[seg*8+7][ldb]=v1.w;
    __syncthreads();
#pragma unroll 4
    for (int kk=0; kk<32; kk++){
      const float* wr = We + (size_t)(kbase+kk)*LAT + lq*8;
      float4 w0 = *(const float4*)wr;
      float4 w1 = *(const float4*)(wr+4);
      float4 z  = *(const float4*)(&sht[kk][bq*4]);
      float wv[8] = {w0.x,w0.y,w0.z,w0.w,w1.x,w1.y,w1.z,w1.w};
      float zv[4] = {z.x,z.y,z.z,z.w};
#pragma unroll
      for (int li=0;li<8;li++)
#pragma unroll
        for (int bi=0;bi<4;bi++) acc[li][bi] += wv[li]*zv[bi];
    }
  }
  float* pp = partial + (size_t)blk*(BN*LAT);
#pragma unroll
  for (int bi=0;bi<4;bi++){
    int b = bq*4+bi;
    float4 o0 = make_float4(acc[0][bi],acc[1][bi],acc[2][bi],acc[3][bi]);
    float4 o1 = make_float4(acc[4][bi],acc[5][bi],acc[6][bi],acc[7][bi]);
    *(float4*)(pp + b*LAT + lq*8)   = o0;
    *(float4*)(pp + b*LAT + lq*8+4) = o1;
  }
}

// ---------------- kernel 3a: coalesced partial reduce: 1256 -> 8 -------------
__global__ __launch_bounds__(256) void k_red1(
    const float* __restrict__ partial, float* __restrict__ partial2)
{
  int idx = blockIdx.x*256 + threadIdx.x;   // 0..8191
  int g = blockIdx.y;                        // 0..7
  float s = 0.f;
  for (int j=0;j<RED_J;j++)
    s += partial[(size_t)(g + RED_G*j)*(BN*LAT) + idx];
  partial2[(size_t)g*(BN*LAT) + idx] = s;
}

// ---------------- kernel 3b: 8 -> zT[l][b] + bias ----------------------------
__global__ __launch_bounds__(256) void k_red2(
    const float* __restrict__ partial2, const float* __restrict__ b_enc,
    float* __restrict__ zT)
{
  int idx = blockIdx.x*256 + threadIdx.x;   // 0..8191 : b*128+l
  float s = 0.f;
#pragma unroll
  for (int g=0; g<RED_G; g++) s += partial2[(size_t)g*(BN*LAT) + idx];
  int b = idx >> 7, l = idx & 127;
  zT[l*BN + b] = s + b_enc[l];
}

// ---------------- kernel 4: decoder  d[b][vc] = z[b]·W_dec[:,vc] + b_dec -----
__global__ __launch_bounds__(256, 4) void k_dec(
    const float* __restrict__ zT, const float* __restrict__ Wd,
    const float* __restrict__ b_dec, float* __restrict__ d)
{
  int vc = blockIdx.x*256 + threadIdx.x;
  if (vc >= KTOT) return;
  float acc[BN];
#pragma unroll
  for (int b=0;b<BN;b++) acc[b]=0.f;
  for (int l=0;l<LAT;l++){
    float w = Wd[(size_t)l*KTOT + vc];
    const float* zr = zT + l*BN;     // wave-uniform -> scalar loads
#pragma unroll
    for (int bb=0;bb<16;bb++){
      float4 z = *(const float4*)(zr + bb*4);
      acc[bb*4+0] += z.x*w; acc[bb*4+1] += z.y*w;
      acc[bb*4+2] += z.z*w; acc[bb*4+3] += z.w*w;
    }
  }
  float bd = b_dec[vc];
#pragma unroll
  for (int b=0;b<BN;b++) d[(size_t)b*KTOT + vc] = acc[b] + bd;
}

// ---------------- kernel 5: per-vertex T[9] and G[27] precompute -------------
__global__ __launch_bounds__(256, 4) void k_tg(
    const float* __restrict__ d, const float* __restrict__ u_d,
    const float* __restrict__ W_d, float* __restrict__ TG)
{
  int t = blockIdx.x*256 + threadIdx.x;
  if (t >= NBV) return;
  const float* drow = d + (size_t)t*CH;
  float T[MN], G[27];
#pragma unroll
  for (int m=0;m<MN;m++) T[m]=0.f;
#pragma unroll
  for (int i=0;i<27;i++) G[i]=0.f;
  for (int c0=0;c0<CH;c0+=4){
    float4 dv = *(const float4*)(drow+c0);
    float dvv[4] = {dv.x,dv.y,dv.z,dv.w};
#pragma unroll
    for (int j=0;j<4;j++){
      int c = c0+j;
      float xv = dvv[j];
#pragma unroll
      for (int m=0;m<MN;m++) T[m] += xv*u_d[c*MN+m];
#pragma unroll
      for (int m=0;m<MN;m++){
        G[m*3+0] += xv*W_d[(m*CH+c)*3+0];
        G[m*3+1] += xv*W_d[(m*CH+c)*3+1];
        G[m*3+2] += xv*W_d[(m*CH+c)*3+2];
      }
    }
  }
  float* tg = TG + (size_t)t*36;
  float rr[36] = {T[0],T[1],T[2],T[3],T[4],T[5],T[6],T[7],T[8],
                  G[0],G[1],G[2],G[3],G[4],G[5],G[6],G[7],G[8],
                  G[9],G[10],G[11],G[12],G[13],G[14],G[15],G[16],G[17],
                  G[18],G[19],G[20],G[21],G[22],G[23],G[24],G[25],G[26]};
#pragma unroll
  for (int i=0;i<36;i+=4)
    *(float4*)(tg+i) = make_float4(rr[i],rr[i+1],rr[i+2],rr[i+3]);
}

// ---------------- kernel 6: attention + output -------------------------------
__global__ __launch_bounds__(256, 4) void k_att(
    const float* __restrict__ TG, const float* __restrict__ aw,
    const int* __restrict__ dst, const float* __restrict__ c_d,
    const float* __restrict__ b_d, float* __restrict__ out)
{
  int t = blockIdx.x*256 + threadIdx.x;
  if (t >= NBV) return;
  int b = t / VN, v = t - b*VN;
  const float* TGb = TG + (size_t)b*VN*36;
  float Ti[MN];
#pragma unroll
  for (int m=0;m<MN;m++) Ti[m] = TGb[(size_t)v*36+m] + c_d[m];
  float y0=0.f, y1=0.f, y2=0.f;
  for (int k=0;k<KN;k++){
    int e = v*KN+k;
    int j = dst[e];
    float awe = aw[e];
    const float* Rp = TGb + (size_t)j*36;
    float4 q0=*(const float4*)(Rp+ 0), q1=*(const float4*)(Rp+ 4),
           q2=*(const float4*)(Rp+ 8), q3=*(const float4*)(Rp+12),
           q4=*(const float4*)(Rp+16), q5=*(const float4*)(Rp+20),
           q6=*(const float4*)(Rp+24), q7=*(const float4*)(Rp+28),
           q8=*(const float4*)(Rp+32);
    float rr[36] = {q0.x,q0.y,q0.z,q0.w, q1.x,q1.y,q1.z,q1.w,
                    q2.x,q2.y,q2.z,q2.w, q3.x,q3.y,q3.z,q3.w,
                    q4.x,q4.y,q4.z,q4.w, q5.x,q5.y,q5.z,q5.w,
                    q6.x,q6.y,q6.z,q6.w, q7.x,q7.y,q7.z,q7.w,
                    q8.x,q8.y,q8.z,q8.w};
    float lg[MN];
#pragma unroll
    for (int m=0;m<MN;m++) lg[m] = Ti[m] - rr[m];
    float mx = lg[0];
#pragma unroll
    for (int m=1;m<MN;m++) mx = fmaxf(mx, lg[m]);
    float ex[MN], s=0.f;
#pragma unroll
    for (int m=0;m<MN;m++){ ex[m] = __expf(lg[m]-mx); s += ex[m]; }
    float sc = awe / s;
#pragma unroll
    for (int m=0;m<MN;m++){
      float a = ex[m]*sc;
      y0 += a*rr[9+m*3+0]; y1 += a*rr[9+m*3+1]; y2 += a*rr[9+m*3+2];
    }
  }
  float* o = out + (size_t)t*3;
  o[0]=fmaxf(y0+b_d[0],0.f); o[1]=fmaxf(y1+b_d[1],0.f); o[2]=fmaxf(y2+b_d[2],0.f);
}

extern "C" void kernel_launch(void* const* d_in, const int* in_sizes, int n_in,
                              void* d_out, int out_size, void* d_ws, size_t ws_size,
                              hipStream_t stream) {
  const float* x     = (const float*)d_in[0];
  const float* aw    = (const float*)d_in[1];
  const float* u_e   = (const float*)d_in[2];
  const float* c_e   = (const float*)d_in[3];
  const float* W_e   = (const float*)d_in[4];
  const float* b_e   = (const float*)d_in[5];
  const float* W_enc = (const float*)d_in[6];
  const float* b_enc = (const float*)d_in[7];
  const float* W_dec = (const float*)d_in[8];
  const float* b_dec = (const float*)d_in[9];
  const float* u_d   = (const float*)d_in[10];
  const float* c_d   = (const float*)d_in[11];
  const float* W_d   = (const float*)d_in[12];
  const float* b_d   = (const float*)d_in[13];
  const int*   dst   = (const int*)d_in[15];
  float* out = (float*)d_out;

  char* ws = (char*)d_ws;
  float* hbuf = (float*)ws;                               // 82.3 MB (h, then d)
  size_t off1 = (size_t)NBV*CH*sizeof(float);
  float* partial = (float*)(ws + off1);                   // 41.2 MB
  float* TGbuf   = (float*)(ws + off1);                   // 46.3 MB (overlaps partial)
  size_t offz = off1 + (size_t)NCHUNK*(BN*LAT)*sizeof(float);
  float* zT       = (float*)(ws + offz);                  // 32 KB
  float* partial2 = (float*)(ws + offz + (size_t)(BN*LAT)*sizeof(float)); // 256 KB
  // timeline: partial dead after red1; partial2 dead after red2; zT dead after dec;
  // TG (written by k_tg, after dec) may overwrite all of them.

  int grid_bv = (NBV + 255)/256;   // 1256

  k_conv1<<<grid_bv,256,0,stream>>>(x, aw, dst, u_e, c_e, W_e, b_e, hbuf);
  k_enc<<<NCHUNK,256,0,stream>>>(hbuf, W_enc, partial);
  dim3 gr1(32, RED_G);
  k_red1<<<gr1,256,0,stream>>>(partial, partial2);
  k_red2<<<32,256,0,stream>>>(partial2, b_enc, zT);
  k_dec<<<grid_bv,256,0,stream>>>(zT, W_dec, b_dec, hbuf);   // d overwrites h
  k_tg<<<grid_bv,256,0,stream>>>(hbuf, u_d, W_d, TGbuf);
  k_att<<<grid_bv,256,0,stream>>>(TGbuf, aw, dst, c_d, b_d, out);
}

// Round 4
// 393.906 us; speedup vs baseline: 1.2342x; 1.2342x over previous
//
#include <hip/hip_runtime.h>

#define VN 5023
#define KN 8
#define BN 64
#define CIN 3
#define CH 64
#define MN 9
#define LAT 128
#define KTOT (VN*CH)      // 321472
#define NBV (BN*VN)       // 321472
#define KC 256
#define NCHUNK 1256       // ceil(KTOT/KC); last chunk has 192 = 6*32 valid k
#define RED_G 8
#define RED_J 157         // 1256 = 8*157 exactly

// ---------------- kernel 1: conv1 (x[B,V,3] -> h[B,V,64], relu) --------------
__global__ __launch_bounds__(256, 4) void k_conv1(
    const float* __restrict__ x, const float* __restrict__ aw,
    const int* __restrict__ dst,
    const float* __restrict__ u_e, const float* __restrict__ c_e,
    const float* __restrict__ W_e, const float* __restrict__ b_e,
    float* __restrict__ h)
{
  int t = blockIdx.x*256 + threadIdx.x;
  if (t >= NBV) return;
  int b = t / VN, v = t - b*VN;
  const float* xb = x + (size_t)b*VN*CIN;
  float xi0 = xb[v*3+0], xi1 = xb[v*3+1], xi2 = xb[v*3+2];
  float Ti[MN];
#pragma unroll
  for (int m=0;m<MN;m++)
    Ti[m] = xi0*u_e[m] + xi1*u_e[MN+m] + xi2*u_e[2*MN+m] + c_e[m];
  float agg[27];
#pragma unroll
  for (int i=0;i<27;i++) agg[i]=0.f;
  for (int k=0;k<KN;k++){
    int e = v*KN+k;
    int j = dst[e];
    float awe = aw[e];
    float xj0 = xb[j*3+0], xj1 = xb[j*3+1], xj2 = xb[j*3+2];
    float lg[MN];
#pragma unroll
    for (int m=0;m<MN;m++)
      lg[m] = Ti[m] - (xj0*u_e[m]+xj1*u_e[MN+m]+xj2*u_e[2*MN+m]);
    float mx = lg[0];
#pragma unroll
    for (int m=1;m<MN;m++) mx = fmaxf(mx, lg[m]);
    float ex[MN], s=0.f;
#pragma unroll
    for (int m=0;m<MN;m++){ ex[m] = __expf(lg[m]-mx); s += ex[m]; }
    float r = awe / s;
#pragma unroll
    for (int m=0;m<MN;m++){
      float a = ex[m]*r;
      agg[m*3+0] += a*xj0; agg[m*3+1] += a*xj1; agg[m*3+2] += a*xj2;
    }
  }
  float* hr = h + (size_t)t*CH;
  // chunked output transform: only 16 accumulators live at a time (no spill)
  for (int cc=0; cc<4; cc++){
    float y[16];
#pragma unroll
    for (int c=0;c<16;c++) y[c] = b_e[cc*16+c];
#pragma unroll
    for (int mc=0; mc<27; mc++){
      float a = agg[mc];
#pragma unroll
      for (int c=0;c<16;c++) y[c] += a * W_e[mc*CH + cc*16 + c];
    }
#pragma unroll
    for (int c=0;c<16;c+=4){
      float4 o = make_float4(fmaxf(y[c],0.f),fmaxf(y[c+1],0.f),
                             fmaxf(y[c+2],0.f),fmaxf(y[c+3],0.f));
      *(float4*)(hr + cc*16 + c) = o;
    }
  }
}

// ---------------- kernel 2: encoder split-K partials -------------------------
// partial[blk][b][l] = sum_{k in chunk} h[b][k] * W_enc[k][l]
// T14 pipelined staging: issue next tile's global loads (coalesced We 16KB +
// h gather 8KB) into regs BEFORE the 32-kk compute phase; ds_write after.
// Inner loop is pure LDS + FMA. One barrier per chunk.
__global__ __launch_bounds__(256, 4) void k_enc(
    const float* __restrict__ h, const float* __restrict__ We,
    float* __restrict__ partial)
{
  __shared__ float wlds[2][32*128];   // 2 x 16 KB, [kk][l] linear
  __shared__ float hlds[2][32][68];   // 2 x 8.7 KB, [kk][b] padded
  int t = threadIdx.x;
  int blk = blockIdx.x;
  int lq = t & 15;                  // l = lq*8 .. +7
  int bq = t >> 4;                  // b = bq*4 .. +3
  float acc[8][4];
#pragma unroll
  for (int i=0;i<8;i++)
#pragma unroll
    for (int j=0;j<4;j++) acc[i][j]=0.f;
  int kbase0 = blk*KC;
  int ldb = t & 63;                 // staging b row
  int seg = t >> 6;                 // staging k-octet: k = seg*8 .. +7
  int nt0 = (blk == NCHUNK-1) ? 6 : 8;   // last chunk: 192 valid k (uniform)

  // prologue: stage tile 0
  float4 wreg0, wreg1, wreg2, wreg3, hreg0, hreg1;
  {
    const float* wsrc = We + (size_t)kbase0*LAT;
    wreg0 = *(const float4*)(wsrc + 0*1024 + t*4);
    wreg1 = *(const float4*)(wsrc + 1*1024 + t*4);
    wreg2 = *(const float4*)(wsrc + 2*1024 + t*4);
    wreg3 = *(const float4*)(wsrc + 3*1024 + t*4);
    const float* hsrc = h + (size_t)ldb*KTOT + kbase0 + seg*8;
    hreg0 = *(const float4*)(hsrc);
    hreg1 = *(const float4*)(hsrc + 4);
    *(float4*)(&wlds[0][0*1024 + t*4]) = wreg0;
    *(float4*)(&wlds[0][1*1024 + t*4]) = wreg1;
    *(float4*)(&wlds[0][2*1024 + t*4]) = wreg2;
    *(float4*)(&wlds[0][3*1024 + t*4]) = wreg3;
    hlds[0][seg*8+0][ldb]=hreg0.x; hlds[0][seg*8+1][ldb]=hreg0.y;
    hlds[0][seg*8+2][ldb]=hreg0.z; hlds[0][seg*8+3][ldb]=hreg0.w;
    hlds[0][seg*8+4][ldb]=hreg1.x; hlds[0][seg*8+5][ldb]=hreg1.y;
    hlds[0][seg*8+6][ldb]=hreg1.z; hlds[0][seg*8+7][ldb]=hreg1.w;
  }
  __syncthreads();

  int cur = 0;
  for (int t0=0; t0<nt0; t0++){
    bool pf = (t0+1 < nt0);
    if (pf){
      int kbase = kbase0 + (t0+1)*32;
      const float* wsrc = We + (size_t)kbase*LAT;
      wreg0 = *(const float4*)(wsrc + 0*1024 + t*4);
      wreg1 = *(const float4*)(wsrc + 1*1024 + t*4);
      wreg2 = *(const float4*)(wsrc + 2*1024 + t*4);
      wreg3 = *(const float4*)(wsrc + 3*1024 + t*4);
      const float* hsrc = h + (size_t)ldb*KTOT + kbase + seg*8;
      hreg0 = *(const float4*)(hsrc);
      hreg1 = *(const float4*)(hsrc + 4);
    }
    __builtin_amdgcn_sched_barrier(0);   // pin prefetch issue before compute
    // compute 32 kk from LDS[cur]
#pragma unroll 4
    for (int kk=0; kk<32; kk++){
      const float* wr = &wlds[cur][kk*128 + lq*8];
      float4 w0 = *(const float4*)wr;
      float4 w1 = *(const float4*)(wr+4);
      float4 z  = *(const float4*)(&hlds[cur][kk][bq*4]);
      float wv[8] = {w0.x,w0.y,w0.z,w0.w,w1.x,w1.y,w1.z,w1.w};
      float zv[4] = {z.x,z.y,z.z,z.w};
#pragma unroll
      for (int li=0;li<8;li++)
#pragma unroll
        for (int bi=0;bi<4;bi++) acc[li][bi] += wv[li]*zv[bi];
    }
    if (pf){
      int nb = cur^1;
      *(float4*)(&wlds[nb][0*1024 + t*4]) = wreg0;
      *(float4*)(&wlds[nb][1*1024 + t*4]) = wreg1;
      *(float4*)(&wlds[nb][2*1024 + t*4]) = wreg2;
      *(float4*)(&wlds[nb][3*1024 + t*4]) = wreg3;
      hlds[nb][seg*8+0][ldb]=hreg0.x; hlds[nb][seg*8+1][ldb]=hreg0.y;
      hlds[nb][seg*8+2][ldb]=hreg0.z; hlds[nb][seg*8+3][ldb]=hreg0.w;
      hlds[nb][seg*8+4][ldb]=hreg1.x; hlds[nb][seg*8+5][ldb]=hreg1.y;
      hlds[nb][seg*8+6][ldb]=hreg1.z; hlds[nb][seg*8+7][ldb]=hreg1.w;
    }
    __syncthreads();
    cur ^= 1;
  }
  float* pp = partial + (size_t)blk*(BN*LAT);
#pragma unroll
  for (int bi=0;bi<4;bi++){
    int b = bq*4+bi;
    float4 o0 = make_float4(acc[0][bi],acc[1][bi],acc[2][bi],acc[3][bi]);
    float4 o1 = make_float4(acc[4][bi],acc[5][bi],acc[6][bi],acc[7][bi]);
    *(float4*)(pp + b*LAT + lq*8)   = o0;
    *(float4*)(pp + b*LAT + lq*8+4) = o1;
  }
}

// ---------------- kernel 3a: coalesced partial reduce: 1256 -> 8 -------------
__global__ __launch_bounds__(256) void k_red1(
    const float* __restrict__ partial, float* __restrict__ partial2)
{
  int idx = blockIdx.x*256 + threadIdx.x;   // 0..8191
  int g = blockIdx.y;                        // 0..7
  float s = 0.f;
  for (int j=0;j<RED_J;j++)
    s += partial[(size_t)(g + RED_G*j)*(BN*LAT) + idx];
  partial2[(size_t)g*(BN*LAT) + idx] = s;
}

// ---------------- kernel 3b: 8 -> zT[l][b] + bias ----------------------------
__global__ __launch_bounds__(256) void k_red2(
    const float* __restrict__ partial2, const float* __restrict__ b_enc,
    float* __restrict__ zT)
{
  int idx = blockIdx.x*256 + threadIdx.x;   // 0..8191 : b*128+l
  float s = 0.f;
#pragma unroll
  for (int g=0; g<RED_G; g++) s += partial2[(size_t)g*(BN*LAT) + idx];
  int b = idx >> 7, l = idx & 127;
  zT[l*BN + b] = s + b_enc[l];
}

// ---------------- kernel 4: decoder  d[b][vc] = z[b]·W_dec[:,vc] + b_dec -----
__global__ __launch_bounds__(256, 4) void k_dec(
    const float* __restrict__ zT, const float* __restrict__ Wd,
    const float* __restrict__ b_dec, float* __restrict__ d)
{
  int vc = blockIdx.x*256 + threadIdx.x;
  if (vc >= KTOT) return;
  float acc[BN];
#pragma unroll
  for (int b=0;b<BN;b++) acc[b]=0.f;
  for (int l=0;l<LAT;l++){
    float w = Wd[(size_t)l*KTOT + vc];
    const float* zr = zT + l*BN;     // wave-uniform -> scalar loads
#pragma unroll
    for (int bb=0;bb<16;bb++){
      float4 z = *(const float4*)(zr + bb*4);
      acc[bb*4+0] += z.x*w; acc[bb*4+1] += z.y*w;
      acc[bb*4+2] += z.z*w; acc[bb*4+3] += z.w*w;
    }
  }
  float bd = b_dec[vc];
#pragma unroll
  for (int b=0;b<BN;b++) d[(size_t)b*KTOT + vc] = acc[b] + bd;
}

// ---------------- kernel 5: per-vertex T[9] and G[27] precompute -------------
__global__ __launch_bounds__(256, 4) void k_tg(
    const float* __restrict__ d, const float* __restrict__ u_d,
    const float* __restrict__ W_d, float* __restrict__ TG)
{
  int t = blockIdx.x*256 + threadIdx.x;
  if (t >= NBV) return;
  const float* drow = d + (size_t)t*CH;
  float T[MN], G[27];
#pragma unroll
  for (int m=0;m<MN;m++) T[m]=0.f;
#pragma unroll
  for (int i=0;i<27;i++) G[i]=0.f;
  for (int c0=0;c0<CH;c0+=4){
    float4 dv = *(const float4*)(drow+c0);
    float dvv[4] = {dv.x,dv.y,dv.z,dv.w};
#pragma unroll
    for (int j=0;j<4;j++){
      int c = c0+j;
      float xv = dvv[j];
#pragma unroll
      for (int m=0;m<MN;m++) T[m] += xv*u_d[c*MN+m];
#pragma unroll
      for (int m=0;m<MN;m++){
        G[m*3+0] += xv*W_d[(m*CH+c)*3+0];
        G[m*3+1] += xv*W_d[(m*CH+c)*3+1];
        G[m*3+2] += xv*W_d[(m*CH+c)*3+2];
      }
    }
  }
  float* tg = TG + (size_t)t*36;
  float rr[36] = {T[0],T[1],T[2],T[3],T[4],T[5],T[6],T[7],T[8],
                  G[0],G[1],G[2],G[3],G[4],G[5],G[6],G[7],G[8],
                  G[9],G[10],G[11],G[12],G[13],G[14],G[15],G[16],G[17],
                  G[18],G[19],G[20],G[21],G[22],G[23],G[24],G[25],G[26]};
#pragma unroll
  for (int i=0;i<36;i+=4)
    *(float4*)(tg+i) = make_float4(rr[i],rr[i+1],rr[i+2],rr[i+3]);
}

// ---------------- kernel 6: attention + output -------------------------------
__global__ __launch_bounds__(256, 4) void k_att(
    const float* __restrict__ TG, const float* __restrict__ aw,
    const int* __restrict__ dst, const float* __restrict__ c_d,
    const float* __restrict__ b_d, float* __restrict__ out)
{
  int t = blockIdx.x*256 + threadIdx.x;
  if (t >= NBV) return;
  int b = t / VN, v = t - b*VN;
  const float* TGb = TG + (size_t)b*VN*36;
  float Ti[MN];
#pragma unroll
  for (int m=0;m<MN;m++) Ti[m] = TGb[(size_t)v*36+m] + c_d[m];
  float y0=0.f, y1=0.f, y2=0.f;
  for (int k=0;k<KN;k++){
    int e = v*KN+k;
    int j = dst[e];
    float awe = aw[e];
    const float* Rp = TGb + (size_t)j*36;
    float4 q0=*(const float4*)(Rp+ 0), q1=*(const float4*)(Rp+ 4),
           q2=*(const float4*)(Rp+ 8), q3=*(const float4*)(Rp+12),
           q4=*(const float4*)(Rp+16), q5=*(const float4*)(Rp+20),
           q6=*(const float4*)(Rp+24), q7=*(const float4*)(Rp+28),
           q8=*(const float4*)(Rp+32);
    float rr[36] = {q0.x,q0.y,q0.z,q0.w, q1.x,q1.y,q1.z,q1.w,
                    q2.x,q2.y,q2.z,q2.w, q3.x,q3.y,q3.z,q3.w,
                    q4.x,q4.y,q4.z,q4.w, q5.x,q5.y,q5.z,q5.w,
                    q6.x,q6.y,q6.z,q6.w, q7.x,q7.y,q7.z,q7.w,
                    q8.x,q8.y,q8.z,q8.w};
    float lg[MN];
#pragma unroll
    for (int m=0;m<MN;m++) lg[m] = Ti[m] - rr[m];
    float mx = lg[0];
#pragma unroll
    for (int m=1;m<MN;m++) mx = fmaxf(mx, lg[m]);
    float ex[MN], s=0.f;
#pragma unroll
    for (int m=0;m<MN;m++){ ex[m] = __expf(lg[m]-mx); s += ex[m]; }
    float sc = awe / s;
#pragma unroll
    for (int m=0;m<MN;m++){
      float a = ex[m]*sc;
      y0 += a*rr[9+m*3+0]; y1 += a*rr[9+m*3+1]; y2 += a*rr[9+m*3+2];
    }
  }
  float* o = out + (size_t)t*3;
  o[0]=fmaxf(y0+b_d[0],0.f); o[1]=fmaxf(y1+b_d[1],0.f); o[2]=fmaxf(y2+b_d[2],0.f);
}

extern "C" void kernel_launch(void* const* d_in, const int* in_sizes, int n_in,
                              void* d_out, int out_size, void* d_ws, size_t ws_size,
                              hipStream_t stream) {
  const float* x     = (const float*)d_in[0];
  const float* aw    = (const float*)d_in[1];
  const float* u_e   = (const float*)d_in[2];
  const float* c_e   = (const float*)d_in[3];
  const float* W_e   = (const float*)d_in[4];
  const float* b_e   = (const float*)d_in[5];
  const float* W_enc = (const float*)d_in[6];
  const float* b_enc = (const float*)d_in[7];
  const float* W_dec = (const float*)d_in[8];
  const float* b_dec = (const float*)d_in[9];
  const float* u_d   = (const float*)d_in[10];
  const float* c_d   = (const float*)d_in[11];
  const float* W_d   = (const float*)d_in[12];
  const float* b_d   = (const float*)d_in[13];
  const int*   dst   = (const int*)d_in[15];
  float* out = (float*)d_out;

  char* ws = (char*)d_ws;
  float* hbuf = (float*)ws;                               // 82.3 MB (h, then d)
  size_t off1 = (size_t)NBV*CH*sizeof(float);
  float* partial = (float*)(ws + off1);                   // 41.2 MB
  float* TGbuf   = (float*)(ws + off1);                   // 46.3 MB (overlaps partial)
  size_t offz = off1 + (size_t)NCHUNK*(BN*LAT)*sizeof(float);
  float* zT       = (float*)(ws + offz);                  // 32 KB
  float* partial2 = (float*)(ws + offz + (size_t)(BN*LAT)*sizeof(float)); // 256 KB
  // timeline: partial dead after red1; partial2 dead after red2; zT dead after dec;
  // TG (written by k_tg, after dec) may overwrite all of them.

  int grid_bv = (NBV + 255)/256;   // 1256

  k_conv1<<<grid_bv,256,0,stream>>>(x, aw, dst, u_e, c_e, W_e, b_e, hbuf);
  k_enc<<<NCHUNK,256,0,stream>>>(hbuf, W_enc, partial);
  dim3 gr1(32, RED_G);
  k_red1<<<gr1,256,0,stream>>>(partial, partial2);
  k_red2<<<32,256,0,stream>>>(partial2, b_enc, zT);
  k_dec<<<grid_bv,256,0,stream>>>(zT, W_dec, b_dec, hbuf);   // d overwrites h
  k_tg<<<grid_bv,256,0,stream>>>(hbuf, u_d, W_d, TGbuf);
  k_att<<<grid_bv,256,0,stream>>>(TGbuf, aw, dst, c_d, b_d, out);
}

// Round 5
// 380.384 us; speedup vs baseline: 1.2780x; 1.0355x over previous
//
#include <hip/hip_runtime.h>

#define VN 5023
#define KN 8
#define BN 64
#define CIN 3
#define CH 64
#define MN 9
#define LAT 128
#define KTOT (VN*CH)      // 321472
#define NBV (BN*VN)       // 321472
#define KC 256
#define NCHUNK 1256       // ceil(KTOT/KC); last chunk has 192 = 6*32 valid k
#define RED_G 8
#define RED_J 157         // 1256 = 8*157 exactly
#define NXCD 8

// ---------------- kernel 1: conv1 (x[B,V,3] -> h[B,V,64], relu) --------------
__global__ __launch_bounds__(256, 4) void k_conv1(
    const float* __restrict__ x, const float* __restrict__ aw,
    const int* __restrict__ dst,
    const float* __restrict__ u_e, const float* __restrict__ c_e,
    const float* __restrict__ W_e, const float* __restrict__ b_e,
    float* __restrict__ h)
{
  int t = blockIdx.x*256 + threadIdx.x;
  if (t >= NBV) return;
  int b = t / VN, v = t - b*VN;
  const float* xb = x + (size_t)b*VN*CIN;
  float xi0 = xb[v*3+0], xi1 = xb[v*3+1], xi2 = xb[v*3+2];
  float Ti[MN];
#pragma unroll
  for (int m=0;m<MN;m++)
    Ti[m] = xi0*u_e[m] + xi1*u_e[MN+m] + xi2*u_e[2*MN+m] + c_e[m];
  float agg[27];
#pragma unroll
  for (int i=0;i<27;i++) agg[i]=0.f;
  for (int k=0;k<KN;k++){
    int e = v*KN+k;
    int j = dst[e];
    float awe = aw[e];
    float xj0 = xb[j*3+0], xj1 = xb[j*3+1], xj2 = xb[j*3+2];
    float lg[MN];
#pragma unroll
    for (int m=0;m<MN;m++)
      lg[m] = Ti[m] - (xj0*u_e[m]+xj1*u_e[MN+m]+xj2*u_e[2*MN+m]);
    float mx = lg[0];
#pragma unroll
    for (int m=1;m<MN;m++) mx = fmaxf(mx, lg[m]);
    float ex[MN], s=0.f;
#pragma unroll
    for (int m=0;m<MN;m++){ ex[m] = __expf(lg[m]-mx); s += ex[m]; }
    float r = awe / s;
#pragma unroll
    for (int m=0;m<MN;m++){
      float a = ex[m]*r;
      agg[m*3+0] += a*xj0; agg[m*3+1] += a*xj1; agg[m*3+2] += a*xj2;
    }
  }
  float* hr = h + (size_t)t*CH;
  for (int cc=0; cc<4; cc++){
    float y[16];
#pragma unroll
    for (int c=0;c<16;c++) y[c] = b_e[cc*16+c];
#pragma unroll
    for (int mc=0; mc<27; mc++){
      float a = agg[mc];
#pragma unroll
      for (int c=0;c<16;c++) y[c] += a * W_e[mc*CH + cc*16 + c];
    }
#pragma unroll
    for (int c=0;c<16;c+=4){
      float4 o = make_float4(fmaxf(y[c],0.f),fmaxf(y[c+1],0.f),
                             fmaxf(y[c+2],0.f),fmaxf(y[c+3],0.f));
      *(float4*)(hr + cc*16 + c) = o;
    }
  }
}

// ---------------- kernel 2: encoder split-K partials (pipelined) -------------
__global__ __launch_bounds__(256, 4) void k_enc(
    const float* __restrict__ h, const float* __restrict__ We,
    float* __restrict__ partial)
{
  __shared__ float wlds[2][32*128];   // 2 x 16 KB, [kk][l] linear
  __shared__ float hlds[2][32][68];   // 2 x 8.7 KB, [kk][b] padded
  int t = threadIdx.x;
  int blk = blockIdx.x;
  int lq = t & 15;
  int bq = t >> 4;
  float acc[8][4];
#pragma unroll
  for (int i=0;i<8;i++)
#pragma unroll
    for (int j=0;j<4;j++) acc[i][j]=0.f;
  int kbase0 = blk*KC;
  int ldb = t & 63;
  int seg = t >> 6;
  int nt0 = (blk == NCHUNK-1) ? 6 : 8;

  float4 wreg0, wreg1, wreg2, wreg3, hreg0, hreg1;
  {
    const float* wsrc = We + (size_t)kbase0*LAT;
    wreg0 = *(const float4*)(wsrc + 0*1024 + t*4);
    wreg1 = *(const float4*)(wsrc + 1*1024 + t*4);
    wreg2 = *(const float4*)(wsrc + 2*1024 + t*4);
    wreg3 = *(const float4*)(wsrc + 3*1024 + t*4);
    const float* hsrc = h + (size_t)ldb*KTOT + kbase0 + seg*8;
    hreg0 = *(const float4*)(hsrc);
    hreg1 = *(const float4*)(hsrc + 4);
    *(float4*)(&wlds[0][0*1024 + t*4]) = wreg0;
    *(float4*)(&wlds[0][1*1024 + t*4]) = wreg1;
    *(float4*)(&wlds[0][2*1024 + t*4]) = wreg2;
    *(float4*)(&wlds[0][3*1024 + t*4]) = wreg3;
    hlds[0][seg*8+0][ldb]=hreg0.x; hlds[0][seg*8+1][ldb]=hreg0.y;
    hlds[0][seg*8+2][ldb]=hreg0.z; hlds[0][seg*8+3][ldb]=hreg0.w;
    hlds[0][seg*8+4][ldb]=hreg1.x; hlds[0][seg*8+5][ldb]=hreg1.y;
    hlds[0][seg*8+6][ldb]=hreg1.z; hlds[0][seg*8+7][ldb]=hreg1.w;
  }
  __syncthreads();

  int cur = 0;
  for (int t0=0; t0<nt0; t0++){
    bool pf = (t0+1 < nt0);
    if (pf){
      int kbase = kbase0 + (t0+1)*32;
      const float* wsrc = We + (size_t)kbase*LAT;
      wreg0 = *(const float4*)(wsrc + 0*1024 + t*4);
      wreg1 = *(const float4*)(wsrc + 1*1024 + t*4);
      wreg2 = *(const float4*)(wsrc + 2*1024 + t*4);
      wreg3 = *(const float4*)(wsrc + 3*1024 + t*4);
      const float* hsrc = h + (size_t)ldb*KTOT + kbase + seg*8;
      hreg0 = *(const float4*)(hsrc);
      hreg1 = *(const float4*)(hsrc + 4);
    }
    __builtin_amdgcn_sched_barrier(0);
#pragma unroll 4
    for (int kk=0; kk<32; kk++){
      const float* wr = &wlds[cur][kk*128 + lq*8];
      float4 w0 = *(const float4*)wr;
      float4 w1 = *(const float4*)(wr+4);
      float4 z  = *(const float4*)(&hlds[cur][kk][bq*4]);
      float wv[8] = {w0.x,w0.y,w0.z,w0.w,w1.x,w1.y,w1.z,w1.w};
      float zv[4] = {z.x,z.y,z.z,z.w};
#pragma unroll
      for (int li=0;li<8;li++)
#pragma unroll
        for (int bi=0;bi<4;bi++) acc[li][bi] += wv[li]*zv[bi];
    }
    if (pf){
      int nb = cur^1;
      *(float4*)(&wlds[nb][0*1024 + t*4]) = wreg0;
      *(float4*)(&wlds[nb][1*1024 + t*4]) = wreg1;
      *(float4*)(&wlds[nb][2*1024 + t*4]) = wreg2;
      *(float4*)(&wlds[nb][3*1024 + t*4]) = wreg3;
      hlds[nb][seg*8+0][ldb]=hreg0.x; hlds[nb][seg*8+1][ldb]=hreg0.y;
      hlds[nb][seg*8+2][ldb]=hreg0.z; hlds[nb][seg*8+3][ldb]=hreg0.w;
      hlds[nb][seg*8+4][ldb]=hreg1.x; hlds[nb][seg*8+5][ldb]=hreg1.y;
      hlds[nb][seg*8+6][ldb]=hreg1.z; hlds[nb][seg*8+7][ldb]=hreg1.w;
    }
    __syncthreads();
    cur ^= 1;
  }
  float* pp = partial + (size_t)blk*(BN*LAT);
#pragma unroll
  for (int bi=0;bi<4;bi++){
    int b = bq*4+bi;
    float4 o0 = make_float4(acc[0][bi],acc[1][bi],acc[2][bi],acc[3][bi]);
    float4 o1 = make_float4(acc[4][bi],acc[5][bi],acc[6][bi],acc[7][bi]);
    *(float4*)(pp + b*LAT + lq*8)   = o0;
    *(float4*)(pp + b*LAT + lq*8+4) = o1;
  }
}

// ---------------- kernel 3a: coalesced partial reduce: 1256 -> 8 -------------
__global__ __launch_bounds__(256) void k_red1(
    const float* __restrict__ partial, float* __restrict__ partial2)
{
  int idx = blockIdx.x*256 + threadIdx.x;
  int g = blockIdx.y;
  float s = 0.f;
  for (int j=0;j<RED_J;j++)
    s += partial[(size_t)(g + RED_G*j)*(BN*LAT) + idx];
  partial2[(size_t)g*(BN*LAT) + idx] = s;
}

// ---------------- kernel 3b: 8 -> zT[l][b] + bias ----------------------------
__global__ __launch_bounds__(256) void k_red2(
    const float* __restrict__ partial2, const float* __restrict__ b_enc,
    float* __restrict__ zT)
{
  int idx = blockIdx.x*256 + threadIdx.x;
  float s = 0.f;
#pragma unroll
  for (int g=0; g<RED_G; g++) s += partial2[(size_t)g*(BN*LAT) + idx];
  int b = idx >> 7, l = idx & 127;
  zT[l*BN + b] = s + b_enc[l];
}

// ---------------- kernel 4: decoder  d[b][vc] = z[b]·W_dec[:,vc] + b_dec -----
// thread owns 4 vc (float4 Wd loads) x 16 b; zT staged in LDS (32 KB),
// z reads are wave-uniform broadcasts. 5 mem ops per 64 FMAs.
__global__ __launch_bounds__(256, 4) void k_dec(
    const float* __restrict__ zT, const float* __restrict__ Wd,
    const float* __restrict__ b_dec, float* __restrict__ d)
{
  __shared__ float zz[LAT*BN];    // [l][b], 32 KB
  int t = threadIdx.x;
  {
    const float4* src = (const float4*)zT;
    float4* dst4 = (float4*)zz;
#pragma unroll
    for (int i=0;i<8;i++) dst4[t + 256*i] = src[t + 256*i];
  }
  __syncthreads();
  int vq = t & 63, bq = t >> 6;      // wave-uniform bq
  int vc = blockIdx.x*256 + vq*4;
  bool ok = (vc < KTOT);             // KTOT%4==0 -> vc<KTOT implies vc+3<KTOT
  float acc[4][16];
#pragma unroll
  for (int i=0;i<4;i++)
#pragma unroll
    for (int j=0;j<16;j++) acc[i][j]=0.f;
#pragma unroll 2
  for (int l=0;l<LAT;l++){
    float4 w = ok ? *(const float4*)(Wd + (size_t)l*KTOT + vc)
                  : make_float4(0.f,0.f,0.f,0.f);
    const float* zr = zz + l*BN + bq*16;
    float4 z0 = *(const float4*)(zr);
    float4 z1 = *(const float4*)(zr+4);
    float4 z2 = *(const float4*)(zr+8);
    float4 z3 = *(const float4*)(zr+12);
    float zv[16] = {z0.x,z0.y,z0.z,z0.w, z1.x,z1.y,z1.z,z1.w,
                    z2.x,z2.y,z2.z,z2.w, z3.x,z3.y,z3.z,z3.w};
    float wv[4] = {w.x,w.y,w.z,w.w};
#pragma unroll
    for (int i=0;i<4;i++)
#pragma unroll
      for (int j=0;j<16;j++) acc[i][j] += wv[i]*zv[j];
  }
  if (ok){
    float4 bd = *(const float4*)(b_dec + vc);
    float bdv[4] = {bd.x,bd.y,bd.z,bd.w};
#pragma unroll
    for (int j=0;j<16;j++){
      int b = bq*16 + j;
      float4 o = make_float4(acc[0][j]+bdv[0], acc[1][j]+bdv[1],
                             acc[2][j]+bdv[2], acc[3][j]+bdv[3]);
      *(float4*)(d + (size_t)b*KTOT + vc) = o;
    }
  }
}

// ---------------- kernel 5: per-vertex T[9] and G[27] precompute -------------
__global__ __launch_bounds__(256, 4) void k_tg(
    const float* __restrict__ d, const float* __restrict__ u_d,
    const float* __restrict__ W_d, float* __restrict__ TG)
{
  int t = blockIdx.x*256 + threadIdx.x;
  if (t >= NBV) return;
  const float* drow = d + (size_t)t*CH;
  float T[MN], G[27];
#pragma unroll
  for (int m=0;m<MN;m++) T[m]=0.f;
#pragma unroll
  for (int i=0;i<27;i++) G[i]=0.f;
  for (int c0=0;c0<CH;c0+=4){
    float4 dv = *(const float4*)(drow+c0);
    float dvv[4] = {dv.x,dv.y,dv.z,dv.w};
#pragma unroll
    for (int j=0;j<4;j++){
      int c = c0+j;
      float xv = dvv[j];
#pragma unroll
      for (int m=0;m<MN;m++) T[m] += xv*u_d[c*MN+m];
#pragma unroll
      for (int m=0;m<MN;m++){
        G[m*3+0] += xv*W_d[(m*CH+c)*3+0];
        G[m*3+1] += xv*W_d[(m*CH+c)*3+1];
        G[m*3+2] += xv*W_d[(m*CH+c)*3+2];
      }
    }
  }
  float* tg = TG + (size_t)t*36;
  float rr[36] = {T[0],T[1],T[2],T[3],T[4],T[5],T[6],T[7],T[8],
                  G[0],G[1],G[2],G[3],G[4],G[5],G[6],G[7],G[8],
                  G[9],G[10],G[11],G[12],G[13],G[14],G[15],G[16],G[17],
                  G[18],G[19],G[20],G[21],G[22],G[23],G[24],G[25],G[26]};
#pragma unroll
  for (int i=0;i<36;i+=4)
    *(float4*)(tg+i) = make_float4(rr[i],rr[i+1],rr[i+2],rr[i+3]);
}

// ---------------- kernel 6: attention + output -------------------------------
// XCD-chunked swizzle (1256 = 8*157, bijective) for TG L2 locality;
// 2-deep edge pipeline: issue edge k+1's 9 gathers before computing edge k.
__global__ __launch_bounds__(256, 4) void k_att(
    const float* __restrict__ TG, const float* __restrict__ aw,
    const int* __restrict__ dst, const float* __restrict__ c_d,
    const float* __restrict__ b_d, float* __restrict__ out)
{
  int wg = blockIdx.x;
  int wgid = (wg & 7)*157 + (wg >> 3);    // chunk per XCD
  int t = wgid*256 + threadIdx.x;
  if (t >= NBV) return;
  int b = t / VN, v = t - b*VN;
  const float* TGb = TG + (size_t)b*VN*36;
  int e0 = v*KN;
  int4 j01 = *(const int4*)(dst + e0);
  int4 j23 = *(const int4*)(dst + e0 + 4);
  int jj[8] = {j01.x,j01.y,j01.z,j01.w, j23.x,j23.y,j23.z,j23.w};
  float4 a01 = *(const float4*)(aw + e0);
  float4 a23 = *(const float4*)(aw + e0 + 4);
  float awv[8] = {a01.x,a01.y,a01.z,a01.w, a23.x,a23.y,a23.z,a23.w};
  float Ti[MN];
#pragma unroll
  for (int m=0;m<MN;m++) Ti[m] = TGb[(size_t)v*36+m] + c_d[m];
  float y0=0.f, y1=0.f, y2=0.f;
  // prefetch edge 0
  float4 q[9];
  {
    const float* Rp = TGb + (size_t)jj[0]*36;
#pragma unroll
    for (int i=0;i<9;i++) q[i] = *(const float4*)(Rp + i*4);
  }
#pragma unroll
  for (int k=0;k<KN;k++){
    float4 p[9];
    if (k+1 < KN){
      const float* Rp = TGb + (size_t)jj[k+1]*36;
#pragma unroll
      for (int i=0;i<9;i++) p[i] = *(const float4*)(Rp + i*4);
    }
    float rr[36] = {q[0].x,q[0].y,q[0].z,q[0].w, q[1].x,q[1].y,q[1].z,q[1].w,
                    q[2].x,q[2].y,q[2].z,q[2].w, q[3].x,q[3].y,q[3].z,q[3].w,
                    q[4].x,q[4].y,q[4].z,q[4].w, q[5].x,q[5].y,q[5].z,q[5].w,
                    q[6].x,q[6].y,q[6].z,q[6].w, q[7].x,q[7].y,q[7].z,q[7].w,
                    q[8].x,q[8].y,q[8].z,q[8].w};
    float lg[MN];
#pragma unroll
    for (int m=0;m<MN;m++) lg[m] = Ti[m] - rr[m];
    float mx = lg[0];
#pragma unroll
    for (int m=1;m<MN;m++) mx = fmaxf(mx, lg[m]);
    float ex[MN], s=0.f;
#pragma unroll
    for (int m=0;m<MN;m++){ ex[m] = __expf(lg[m]-mx); s += ex[m]; }
    float sc = awv[k] / s;
#pragma unroll
    for (int m=0;m<MN;m++){
      float a = ex[m]*sc;
      y0 += a*rr[9+m*3+0]; y1 += a*rr[9+m*3+1]; y2 += a*rr[9+m*3+2];
    }
    if (k+1 < KN){
#pragma unroll
      for (int i=0;i<9;i++) q[i] = p[i];
    }
  }
  float* o = out + (size_t)t*3;
  o[0]=fmaxf(y0+b_d[0],0.f); o[1]=fmaxf(y1+b_d[1],0.f); o[2]=fmaxf(y2+b_d[2],0.f);
}

extern "C" void kernel_launch(void* const* d_in, const int* in_sizes, int n_in,
                              void* d_out, int out_size, void* d_ws, size_t ws_size,
                              hipStream_t stream) {
  const float* x     = (const float*)d_in[0];
  const float* aw    = (const float*)d_in[1];
  const float* u_e   = (const float*)d_in[2];
  const float* c_e   = (const float*)d_in[3];
  const float* W_e   = (const float*)d_in[4];
  const float* b_e   = (const float*)d_in[5];
  const float* W_enc = (const float*)d_in[6];
  const float* b_enc = (const float*)d_in[7];
  const float* W_dec = (const float*)d_in[8];
  const float* b_dec = (const float*)d_in[9];
  const float* u_d   = (const float*)d_in[10];
  const float* c_d   = (const float*)d_in[11];
  const float* W_d   = (const float*)d_in[12];
  const float* b_d   = (const float*)d_in[13];
  const int*   dst   = (const int*)d_in[15];
  float* out = (float*)d_out;

  char* ws = (char*)d_ws;
  float* hbuf = (float*)ws;                               // 82.3 MB (h, then d)
  size_t off1 = (size_t)NBV*CH*sizeof(float);
  float* partial = (float*)(ws + off1);                   // 41.2 MB
  float* TGbuf   = (float*)(ws + off1);                   // 46.3 MB (overlaps partial)
  size_t offz = off1 + (size_t)NCHUNK*(BN*LAT)*sizeof(float);
  float* zT       = (float*)(ws + offz);                  // 32 KB
  float* partial2 = (float*)(ws + offz + (size_t)(BN*LAT)*sizeof(float)); // 256 KB

  int grid_bv = (NBV + 255)/256;   // 1256

  k_conv1<<<grid_bv,256,0,stream>>>(x, aw, dst, u_e, c_e, W_e, b_e, hbuf);
  k_enc<<<NCHUNK,256,0,stream>>>(hbuf, W_enc, partial);
  dim3 gr1(32, RED_G);
  k_red1<<<gr1,256,0,stream>>>(partial, partial2);
  k_red2<<<32,256,0,stream>>>(partial2, b_enc, zT);
  int grid_dec = (KTOT + 255)/256;   // 1256
  k_dec<<<grid_dec,256,0,stream>>>(zT, W_dec, b_dec, hbuf);   // d overwrites h
  k_tg<<<grid_bv,256,0,stream>>>(hbuf, u_d, W_d, TGbuf);
  k_att<<<grid_bv,256,0,stream>>>(TGbuf, aw, dst, c_d, b_d, out);
}

// Round 6
// 368.587 us; speedup vs baseline: 1.3189x; 1.0320x over previous
//
#include <hip/hip_runtime.h>

#define VN 5023
#define KN 8
#define BN 64
#define CIN 3
#define CH 64
#define MN 9
#define LAT 128
#define KTOT (VN*CH)      // 321472
#define NBV (BN*VN)       // 321472
#define KC 256
#define NCHUNK 1256       // ceil(KTOT/KC); last chunk has 192 = 6*32 valid k
#define RED_G 8
#define RED_J 157         // 1256 = 8*157 exactly
#define NXCD 8

// ---------------- kernel 1: conv1 (x[B,V,3] -> h[B,V,64], relu) --------------
__global__ __launch_bounds__(256, 4) void k_conv1(
    const float* __restrict__ x, const float* __restrict__ aw,
    const int* __restrict__ dst,
    const float* __restrict__ u_e, const float* __restrict__ c_e,
    const float* __restrict__ W_e, const float* __restrict__ b_e,
    float* __restrict__ h)
{
  int t = blockIdx.x*256 + threadIdx.x;
  if (t >= NBV) return;
  int b = t / VN, v = t - b*VN;
  const float* xb = x + (size_t)b*VN*CIN;
  float xi0 = xb[v*3+0], xi1 = xb[v*3+1], xi2 = xb[v*3+2];
  float Ti[MN];
#pragma unroll
  for (int m=0;m<MN;m++)
    Ti[m] = xi0*u_e[m] + xi1*u_e[MN+m] + xi2*u_e[2*MN+m] + c_e[m];
  float agg[27];
#pragma unroll
  for (int i=0;i<27;i++) agg[i]=0.f;
  for (int k=0;k<KN;k++){
    int e = v*KN+k;
    int j = dst[e];
    float awe = aw[e];
    float xj0 = xb[j*3+0], xj1 = xb[j*3+1], xj2 = xb[j*3+2];
    float lg[MN];
#pragma unroll
    for (int m=0;m<MN;m++)
      lg[m] = Ti[m] - (xj0*u_e[m]+xj1*u_e[MN+m]+xj2*u_e[2*MN+m]);
    float mx = lg[0];
#pragma unroll
    for (int m=1;m<MN;m++) mx = fmaxf(mx, lg[m]);
    float ex[MN], s=0.f;
#pragma unroll
    for (int m=0;m<MN;m++){ ex[m] = __expf(lg[m]-mx); s += ex[m]; }
    float r = awe / s;
#pragma unroll
    for (int m=0;m<MN;m++){
      float a = ex[m]*r;
      agg[m*3+0] += a*xj0; agg[m*3+1] += a*xj1; agg[m*3+2] += a*xj2;
    }
  }
  float* hr = h + (size_t)t*CH;
  for (int cc=0; cc<4; cc++){
    float y[16];
#pragma unroll
    for (int c=0;c<16;c++) y[c] = b_e[cc*16+c];
#pragma unroll
    for (int mc=0; mc<27; mc++){
      float a = agg[mc];
#pragma unroll
      for (int c=0;c<16;c++) y[c] += a * W_e[mc*CH + cc*16 + c];
    }
#pragma unroll
    for (int c=0;c<16;c+=4){
      float4 o = make_float4(fmaxf(y[c],0.f),fmaxf(y[c+1],0.f),
                             fmaxf(y[c+2],0.f),fmaxf(y[c+3],0.f));
      *(float4*)(hr + cc*16 + c) = o;
    }
  }
}

// ---------------- kernel 2: encoder split-K partials (pipelined) -------------
__global__ __launch_bounds__(256, 4) void k_enc(
    const float* __restrict__ h, const float* __restrict__ We,
    float* __restrict__ partial)
{
  __shared__ float wlds[2][32*128];   // 2 x 16 KB, [kk][l] linear
  __shared__ float hlds[2][32][68];   // 2 x 8.7 KB, [kk][b] padded
  int t = threadIdx.x;
  int blk = blockIdx.x;
  int lq = t & 15;
  int bq = t >> 4;
  float acc[8][4];
#pragma unroll
  for (int i=0;i<8;i++)
#pragma unroll
    for (int j=0;j<4;j++) acc[i][j]=0.f;
  int kbase0 = blk*KC;
  int ldb = t & 63;
  int seg = t >> 6;
  int nt0 = (blk == NCHUNK-1) ? 6 : 8;

  float4 wreg0, wreg1, wreg2, wreg3, hreg0, hreg1;
  {
    const float* wsrc = We + (size_t)kbase0*LAT;
    wreg0 = *(const float4*)(wsrc + 0*1024 + t*4);
    wreg1 = *(const float4*)(wsrc + 1*1024 + t*4);
    wreg2 = *(const float4*)(wsrc + 2*1024 + t*4);
    wreg3 = *(const float4*)(wsrc + 3*1024 + t*4);
    const float* hsrc = h + (size_t)ldb*KTOT + kbase0 + seg*8;
    hreg0 = *(const float4*)(hsrc);
    hreg1 = *(const float4*)(hsrc + 4);
    *(float4*)(&wlds[0][0*1024 + t*4]) = wreg0;
    *(float4*)(&wlds[0][1*1024 + t*4]) = wreg1;
    *(float4*)(&wlds[0][2*1024 + t*4]) = wreg2;
    *(float4*)(&wlds[0][3*1024 + t*4]) = wreg3;
    hlds[0][seg*8+0][ldb]=hreg0.x; hlds[0][seg*8+1][ldb]=hreg0.y;
    hlds[0][seg*8+2][ldb]=hreg0.z; hlds[0][seg*8+3][ldb]=hreg0.w;
    hlds[0][seg*8+4][ldb]=hreg1.x; hlds[0][seg*8+5][ldb]=hreg1.y;
    hlds[0][seg*8+6][ldb]=hreg1.z; hlds[0][seg*8+7][ldb]=hreg1.w;
  }
  __syncthreads();

  int cur = 0;
  for (int t0=0; t0<nt0; t0++){
    bool pf = (t0+1 < nt0);
    if (pf){
      int kbase = kbase0 + (t0+1)*32;
      const float* wsrc = We + (size_t)kbase*LAT;
      wreg0 = *(const float4*)(wsrc + 0*1024 + t*4);
      wreg1 = *(const float4*)(wsrc + 1*1024 + t*4);
      wreg2 = *(const float4*)(wsrc + 2*1024 + t*4);
      wreg3 = *(const float4*)(wsrc + 3*1024 + t*4);
      const float* hsrc = h + (size_t)ldb*KTOT + kbase + seg*8;
      hreg0 = *(const float4*)(hsrc);
      hreg1 = *(const float4*)(hsrc + 4);
    }
    __builtin_amdgcn_sched_barrier(0);
#pragma unroll 4
    for (int kk=0; kk<32; kk++){
      const float* wr = &wlds[cur][kk*128 + lq*8];
      float4 w0 = *(const float4*)wr;
      float4 w1 = *(const float4*)(wr+4);
      float4 z  = *(const float4*)(&hlds[cur][kk][bq*4]);
      float wv[8] = {w0.x,w0.y,w0.z,w0.w,w1.x,w1.y,w1.z,w1.w};
      float zv[4] = {z.x,z.y,z.z,z.w};
#pragma unroll
      for (int li=0;li<8;li++)
#pragma unroll
        for (int bi=0;bi<4;bi++) acc[li][bi] += wv[li]*zv[bi];
    }
    if (pf){
      int nb = cur^1;
      *(float4*)(&wlds[nb][0*1024 + t*4]) = wreg0;
      *(float4*)(&wlds[nb][1*1024 + t*4]) = wreg1;
      *(float4*)(&wlds[nb][2*1024 + t*4]) = wreg2;
      *(float4*)(&wlds[nb][3*1024 + t*4]) = wreg3;
      hlds[nb][seg*8+0][ldb]=hreg0.x; hlds[nb][seg*8+1][ldb]=hreg0.y;
      hlds[nb][seg*8+2][ldb]=hreg0.z; hlds[nb][seg*8+3][ldb]=hreg0.w;
      hlds[nb][seg*8+4][ldb]=hreg1.x; hlds[nb][seg*8+5][ldb]=hreg1.y;
      hlds[nb][seg*8+6][ldb]=hreg1.z; hlds[nb][seg*8+7][ldb]=hreg1.w;
    }
    __syncthreads();
    cur ^= 1;
  }
  float* pp = partial + (size_t)blk*(BN*LAT);
#pragma unroll
  for (int bi=0;bi<4;bi++){
    int b = bq*4+bi;
    float4 o0 = make_float4(acc[0][bi],acc[1][bi],acc[2][bi],acc[3][bi]);
    float4 o1 = make_float4(acc[4][bi],acc[5][bi],acc[6][bi],acc[7][bi]);
    *(float4*)(pp + b*LAT + lq*8)   = o0;
    *(float4*)(pp + b*LAT + lq*8+4) = o1;
  }
}

// ---------------- kernel 3a: coalesced partial reduce: 1256 -> 8 -------------
__global__ __launch_bounds__(256) void k_red1(
    const float* __restrict__ partial, float* __restrict__ partial2)
{
  int idx = blockIdx.x*256 + threadIdx.x;
  int g = blockIdx.y;
  float s = 0.f;
  for (int j=0;j<RED_J;j++)
    s += partial[(size_t)(g + RED_G*j)*(BN*LAT) + idx];
  partial2[(size_t)g*(BN*LAT) + idx] = s;
}

// ---------------- kernel 3b: 8 -> zT[l][b] + bias ----------------------------
__global__ __launch_bounds__(256) void k_red2(
    const float* __restrict__ partial2, const float* __restrict__ b_enc,
    float* __restrict__ zT)
{
  int idx = blockIdx.x*256 + threadIdx.x;
  float s = 0.f;
#pragma unroll
  for (int g=0; g<RED_G; g++) s += partial2[(size_t)g*(BN*LAT) + idx];
  int b = idx >> 7, l = idx & 127;
  zT[l*BN + b] = s + b_enc[l];
}

// ---------------- kernel 4: decoder  d[b][vc] = z[b]·W_dec[:,vc] + b_dec -----
// 512 thr = 8 waves; wave wv owns b = wv*8..+7 (wave-uniform -> z scalarizes
// to s_load, no LDS); lane owns 4 vc -> 32 acc, ~50 VGPR -> 8 waves/SIMD.
// Per l: 1 coalesced dwordx4 (Wd) + 32 FMA.
__global__ __launch_bounds__(512, 8) void k_dec(
    const float* __restrict__ zT, const float* __restrict__ Wd,
    const float* __restrict__ b_dec, float* __restrict__ d)
{
  int t = threadIdx.x;
  int lane = t & 63;
  int wv = __builtin_amdgcn_readfirstlane(t >> 6);   // wave-uniform 0..7
  int vc = blockIdx.x*256 + lane*4;
  bool ok = (vc < KTOT);            // KTOT%4==0 -> vc<KTOT implies vc+3<KTOT
  const float* zrow = zT + wv*8;    // + l*BN, wave-uniform address
  float acc[4][8];
#pragma unroll
  for (int i=0;i<4;i++)
#pragma unroll
    for (int j=0;j<8;j++) acc[i][j]=0.f;
#pragma unroll 2
  for (int l=0;l<LAT;l++){
    float4 w = ok ? *(const float4*)(Wd + (size_t)l*KTOT + vc)
                  : make_float4(0.f,0.f,0.f,0.f);
    float zv[8];
#pragma unroll
    for (int j=0;j<8;j++) zv[j] = zrow[l*BN + j];   // uniform -> s_load
    float wvv[4] = {w.x,w.y,w.z,w.w};
#pragma unroll
    for (int i=0;i<4;i++)
#pragma unroll
      for (int j=0;j<8;j++) acc[i][j] += wvv[i]*zv[j];
  }
  if (ok){
    float4 bd = *(const float4*)(b_dec + vc);
#pragma unroll
    for (int j=0;j<8;j++){
      int b = wv*8 + j;
      float4 o = make_float4(acc[0][j]+bd.x, acc[1][j]+bd.y,
                             acc[2][j]+bd.z, acc[3][j]+bd.w);
      *(float4*)(d + (size_t)b*KTOT + vc) = o;
    }
  }
}

// ---------------- kernel 5: per-vertex T[9] and G[27] precompute -------------
__global__ __launch_bounds__(256, 4) void k_tg(
    const float* __restrict__ d, const float* __restrict__ u_d,
    const float* __restrict__ W_d, float* __restrict__ TG)
{
  int t = blockIdx.x*256 + threadIdx.x;
  if (t >= NBV) return;
  const float* drow = d + (size_t)t*CH;
  float T[MN], G[27];
#pragma unroll
  for (int m=0;m<MN;m++) T[m]=0.f;
#pragma unroll
  for (int i=0;i<27;i++) G[i]=0.f;
  for (int c0=0;c0<CH;c0+=4){
    float4 dv = *(const float4*)(drow+c0);
    float dvv[4] = {dv.x,dv.y,dv.z,dv.w};
#pragma unroll
    for (int j=0;j<4;j++){
      int c = c0+j;
      float xv = dvv[j];
#pragma unroll
      for (int m=0;m<MN;m++) T[m] += xv*u_d[c*MN+m];
#pragma unroll
      for (int m=0;m<MN;m++){
        G[m*3+0] += xv*W_d[(m*CH+c)*3+0];
        G[m*3+1] += xv*W_d[(m*CH+c)*3+1];
        G[m*3+2] += xv*W_d[(m*CH+c)*3+2];
      }
    }
  }
  float* tg = TG + (size_t)t*36;
  float rr[36] = {T[0],T[1],T[2],T[3],T[4],T[5],T[6],T[7],T[8],
                  G[0],G[1],G[2],G[3],G[4],G[5],G[6],G[7],G[8],
                  G[9],G[10],G[11],G[12],G[13],G[14],G[15],G[16],G[17],
                  G[18],G[19],G[20],G[21],G[22],G[23],G[24],G[25],G[26]};
#pragma unroll
  for (int i=0;i<36;i+=4)
    *(float4*)(tg+i) = make_float4(rr[i],rr[i+1],rr[i+2],rr[i+3]);
}

// ---------------- kernel 6: attention + output -------------------------------
// XCD-chunked swizzle (1256 = 8*157, bijective) for TG L2 locality;
// 2-deep edge pipeline: issue edge k+1's 9 gathers before computing edge k.
__global__ __launch_bounds__(256, 4) void k_att(
    const float* __restrict__ TG, const float* __restrict__ aw,
    const int* __restrict__ dst, const float* __restrict__ c_d,
    const float* __restrict__ b_d, float* __restrict__ out)
{
  int wg = blockIdx.x;
  int wgid = (wg & 7)*157 + (wg >> 3);    // chunk per XCD
  int t = wgid*256 + threadIdx.x;
  if (t >= NBV) return;
  int b = t / VN, v = t - b*VN;
  const float* TGb = TG + (size_t)b*VN*36;
  int e0 = v*KN;
  int4 j01 = *(const int4*)(dst + e0);
  int4 j23 = *(const int4*)(dst + e0 + 4);
  int jj[8] = {j01.x,j01.y,j01.z,j01.w, j23.x,j23.y,j23.z,j23.w};
  float4 a01 = *(const float4*)(aw + e0);
  float4 a23 = *(const float4*)(aw + e0 + 4);
  float awv[8] = {a01.x,a01.y,a01.z,a01.w, a23.x,a23.y,a23.z,a23.w};
  float Ti[MN];
#pragma unroll
  for (int m=0;m<MN;m++) Ti[m] = TGb[(size_t)v*36+m] + c_d[m];
  float y0=0.f, y1=0.f, y2=0.f;
  float4 q[9];
  {
    const float* Rp = TGb + (size_t)jj[0]*36;
#pragma unroll
    for (int i=0;i<9;i++) q[i] = *(const float4*)(Rp + i*4);
  }
#pragma unroll
  for (int k=0;k<KN;k++){
    float4 p[9];
    if (k+1 < KN){
      const float* Rp = TGb + (size_t)jj[k+1]*36;
#pragma unroll
      for (int i=0;i<9;i++) p[i] = *(const float4*)(Rp + i*4);
    }
    float rr[36] = {q[0].x,q[0].y,q[0].z,q[0].w, q[1].x,q[1].y,q[1].z,q[1].w,
                    q[2].x,q[2].y,q[2].z,q[2].w, q[3].x,q[3].y,q[3].z,q[3].w,
                    q[4].x,q[4].y,q[4].z,q[4].w, q[5].x,q[5].y,q[5].z,q[5].w,
                    q[6].x,q[6].y,q[6].z,q[6].w, q[7].x,q[7].y,q[7].z,q[7].w,
                    q[8].x,q[8].y,q[8].z,q[8].w};
    float lg[MN];
#pragma unroll
    for (int m=0;m<MN;m++) lg[m] = Ti[m] - rr[m];
    float mx = lg[0];
#pragma unroll
    for (int m=1;m<MN;m++) mx = fmaxf(mx, lg[m]);
    float ex[MN], s=0.f;
#pragma unroll
    for (int m=0;m<MN;m++){ ex[m] = __expf(lg[m]-mx); s += ex[m]; }
    float sc = awv[k] / s;
#pragma unroll
    for (int m=0;m<MN;m++){
      float a = ex[m]*sc;
      y0 += a*rr[9+m*3+0]; y1 += a*rr[9+m*3+1]; y2 += a*rr[9+m*3+2];
    }
    if (k+1 < KN){
#pragma unroll
      for (int i=0;i<9;i++) q[i] = p[i];
    }
  }
  float* o = out + (size_t)t*3;
  o[0]=fmaxf(y0+b_d[0],0.f); o[1]=fmaxf(y1+b_d[1],0.f); o[2]=fmaxf(y2+b_d[2],0.f);
}

extern "C" void kernel_launch(void* const* d_in, const int* in_sizes, int n_in,
                              void* d_out, int out_size, void* d_ws, size_t ws_size,
                              hipStream_t stream) {
  const float* x     = (const float*)d_in[0];
  const float* aw    = (const float*)d_in[1];
  const float* u_e   = (const float*)d_in[2];
  const float* c_e   = (const float*)d_in[3];
  const float* W_e   = (const float*)d_in[4];
  const float* b_e   = (const float*)d_in[5];
  const float* W_enc = (const float*)d_in[6];
  const float* b_enc = (const float*)d_in[7];
  const float* W_dec = (const float*)d_in[8];
  const float* b_dec = (const float*)d_in[9];
  const float* u_d   = (const float*)d_in[10];
  const float* c_d   = (const float*)d_in[11];
  const float* W_d   = (const float*)d_in[12];
  const float* b_d   = (const float*)d_in[13];
  const int*   dst   = (const int*)d_in[15];
  float* out = (float*)d_out;

  char* ws = (char*)d_ws;
  float* hbuf = (float*)ws;                               // 82.3 MB (h, then d)
  size_t off1 = (size_t)NBV*CH*sizeof(float);
  float* partial = (float*)(ws + off1);                   // 41.2 MB
  float* TGbuf   = (float*)(ws + off1);                   // 46.3 MB (overlaps partial)
  size_t offz = off1 + (size_t)NCHUNK*(BN*LAT)*sizeof(float);  // 256B-aligned
  float* zT       = (float*)(ws + offz);                  // 32 KB
  float* partial2 = (float*)(ws + offz + (size_t)(BN*LAT)*sizeof(float)); // 256 KB

  int grid_bv = (NBV + 255)/256;   // 1256

  k_conv1<<<grid_bv,256,0,stream>>>(x, aw, dst, u_e, c_e, W_e, b_e, hbuf);
  k_enc<<<NCHUNK,256,0,stream>>>(hbuf, W_enc, partial);
  dim3 gr1(32, RED_G);
  k_red1<<<gr1,256,0,stream>>>(partial, partial2);
  k_red2<<<32,256,0,stream>>>(partial2, b_enc, zT);
  int grid_dec = (KTOT + 255)/256;   // 1256 (last block: 192 valid vc)
  k_dec<<<grid_dec,512,0,stream>>>(zT, W_dec, b_dec, hbuf);   // d overwrites h
  k_tg<<<grid_bv,256,0,stream>>>(hbuf, u_d, W_d, TGbuf);
  k_att<<<grid_bv,256,0,stream>>>(TGbuf, aw, dst, c_d, b_d, out);
}

// Round 7
// 352.281 us; speedup vs baseline: 1.3800x; 1.0463x over previous
//
#include <hip/hip_runtime.h>

#define VN 5023
#define KN 8
#define BN 64
#define CIN 3
#define CH 64
#define MN 9
#define LAT 128
#define KTOT (VN*CH)      // 321472
#define NBV (BN*VN)       // 321472
#define KC 256
#define NCHUNK 1256       // ceil(KTOT/KC); last chunk has 192 = 6*32 valid k
#define RED_G 8
#define RED_J 157         // 1256 = 8*157 exactly
#define NXCD 8

// ---------------- kernel 1: conv1 (x[B,V,3] -> h[B,V,64], relu) --------------
__global__ __launch_bounds__(256, 4) void k_conv1(
    const float* __restrict__ x, const float* __restrict__ aw,
    const int* __restrict__ dst,
    const float* __restrict__ u_e, const float* __restrict__ c_e,
    const float* __restrict__ W_e, const float* __restrict__ b_e,
    float* __restrict__ h)
{
  int t = blockIdx.x*256 + threadIdx.x;
  if (t >= NBV) return;
  int b = t / VN, v = t - b*VN;
  const float* xb = x + (size_t)b*VN*CIN;
  float xi0 = xb[v*3+0], xi1 = xb[v*3+1], xi2 = xb[v*3+2];
  float Ti[MN];
#pragma unroll
  for (int m=0;m<MN;m++)
    Ti[m] = xi0*u_e[m] + xi1*u_e[MN+m] + xi2*u_e[2*MN+m] + c_e[m];
  float agg[27];
#pragma unroll
  for (int i=0;i<27;i++) agg[i]=0.f;
  for (int k=0;k<KN;k++){
    int e = v*KN+k;
    int j = dst[e];
    float awe = aw[e];
    float xj0 = xb[j*3+0], xj1 = xb[j*3+1], xj2 = xb[j*3+2];
    float lg[MN];
#pragma unroll
    for (int m=0;m<MN;m++)
      lg[m] = Ti[m] - (xj0*u_e[m]+xj1*u_e[MN+m]+xj2*u_e[2*MN+m]);
    float mx = lg[0];
#pragma unroll
    for (int m=1;m<MN;m++) mx = fmaxf(mx, lg[m]);
    float ex[MN], s=0.f;
#pragma unroll
    for (int m=0;m<MN;m++){ ex[m] = __expf(lg[m]-mx); s += ex[m]; }
    float r = awe / s;
#pragma unroll
    for (int m=0;m<MN;m++){
      float a = ex[m]*r;
      agg[m*3+0] += a*xj0; agg[m*3+1] += a*xj1; agg[m*3+2] += a*xj2;
    }
  }
  float* hr = h + (size_t)t*CH;
  for (int cc=0; cc<4; cc++){
    float y[16];
#pragma unroll
    for (int c=0;c<16;c++) y[c] = b_e[cc*16+c];
#pragma unroll
    for (int mc=0; mc<27; mc++){
      float a = agg[mc];
#pragma unroll
      for (int c=0;c<16;c++) y[c] += a * W_e[mc*CH + cc*16 + c];
    }
#pragma unroll
    for (int c=0;c<16;c+=4){
      float4 o = make_float4(fmaxf(y[c],0.f),fmaxf(y[c+1],0.f),
                             fmaxf(y[c+2],0.f),fmaxf(y[c+3],0.f));
      *(float4*)(hr + cc*16 + c) = o;
    }
  }
}

// ---------------- kernel 2: encoder split-K partials (pipelined) -------------
__global__ __launch_bounds__(256, 4) void k_enc(
    const float* __restrict__ h, const float* __restrict__ We,
    float* __restrict__ partial)
{
  __shared__ float wlds[2][32*128];   // 2 x 16 KB, [kk][l] linear
  __shared__ float hlds[2][32][68];   // 2 x 8.7 KB, [kk][b] padded
  int t = threadIdx.x;
  int blk = blockIdx.x;
  int lq = t & 15;
  int bq = t >> 4;
  float acc[8][4];
#pragma unroll
  for (int i=0;i<8;i++)
#pragma unroll
    for (int j=0;j<4;j++) acc[i][j]=0.f;
  int kbase0 = blk*KC;
  int ldb = t & 63;
  int seg = t >> 6;
  int nt0 = (blk == NCHUNK-1) ? 6 : 8;

  float4 wreg0, wreg1, wreg2, wreg3, hreg0, hreg1;
  {
    const float* wsrc = We + (size_t)kbase0*LAT;
    wreg0 = *(const float4*)(wsrc + 0*1024 + t*4);
    wreg1 = *(const float4*)(wsrc + 1*1024 + t*4);
    wreg2 = *(const float4*)(wsrc + 2*1024 + t*4);
    wreg3 = *(const float4*)(wsrc + 3*1024 + t*4);
    const float* hsrc = h + (size_t)ldb*KTOT + kbase0 + seg*8;
    hreg0 = *(const float4*)(hsrc);
    hreg1 = *(const float4*)(hsrc + 4);
    *(float4*)(&wlds[0][0*1024 + t*4]) = wreg0;
    *(float4*)(&wlds[0][1*1024 + t*4]) = wreg1;
    *(float4*)(&wlds[0][2*1024 + t*4]) = wreg2;
    *(float4*)(&wlds[0][3*1024 + t*4]) = wreg3;
    hlds[0][seg*8+0][ldb]=hreg0.x; hlds[0][seg*8+1][ldb]=hreg0.y;
    hlds[0][seg*8+2][ldb]=hreg0.z; hlds[0][seg*8+3][ldb]=hreg0.w;
    hlds[0][seg*8+4][ldb]=hreg1.x; hlds[0][seg*8+5][ldb]=hreg1.y;
    hlds[0][seg*8+6][ldb]=hreg1.z; hlds[0][seg*8+7][ldb]=hreg1.w;
  }
  __syncthreads();

  int cur = 0;
  for (int t0=0; t0<nt0; t0++){
    bool pf = (t0+1 < nt0);
    if (pf){
      int kbase = kbase0 + (t0+1)*32;
      const float* wsrc = We + (size_t)kbase*LAT;
      wreg0 = *(const float4*)(wsrc + 0*1024 + t*4);
      wreg1 = *(const float4*)(wsrc + 1*1024 + t*4);
      wreg2 = *(const float4*)(wsrc + 2*1024 + t*4);
      wreg3 = *(const float4*)(wsrc + 3*1024 + t*4);
      const float* hsrc = h + (size_t)ldb*KTOT + kbase + seg*8;
      hreg0 = *(const float4*)(hsrc);
      hreg1 = *(const float4*)(hsrc + 4);
    }
    __builtin_amdgcn_sched_barrier(0);
#pragma unroll 4
    for (int kk=0; kk<32; kk++){
      const float* wr = &wlds[cur][kk*128 + lq*8];
      float4 w0 = *(const float4*)wr;
      float4 w1 = *(const float4*)(wr+4);
      float4 z  = *(const float4*)(&hlds[cur][kk][bq*4]);
      float wv[8] = {w0.x,w0.y,w0.z,w0.w,w1.x,w1.y,w1.z,w1.w};
      float zv[4] = {z.x,z.y,z.z,z.w};
#pragma unroll
      for (int li=0;li<8;li++)
#pragma unroll
        for (int bi=0;bi<4;bi++) acc[li][bi] += wv[li]*zv[bi];
    }
    if (pf){
      int nb = cur^1;
      *(float4*)(&wlds[nb][0*1024 + t*4]) = wreg0;
      *(float4*)(&wlds[nb][1*1024 + t*4]) = wreg1;
      *(float4*)(&wlds[nb][2*1024 + t*4]) = wreg2;
      *(float4*)(&wlds[nb][3*1024 + t*4]) = wreg3;
      hlds[nb][seg*8+0][ldb]=hreg0.x; hlds[nb][seg*8+1][ldb]=hreg0.y;
      hlds[nb][seg*8+2][ldb]=hreg0.z; hlds[nb][seg*8+3][ldb]=hreg0.w;
      hlds[nb][seg*8+4][ldb]=hreg1.x; hlds[nb][seg*8+5][ldb]=hreg1.y;
      hlds[nb][seg*8+6][ldb]=hreg1.z; hlds[nb][seg*8+7][ldb]=hreg1.w;
    }
    __syncthreads();
    cur ^= 1;
  }
  float* pp = partial + (size_t)blk*(BN*LAT);
#pragma unroll
  for (int bi=0;bi<4;bi++){
    int b = bq*4+bi;
    float4 o0 = make_float4(acc[0][bi],acc[1][bi],acc[2][bi],acc[3][bi]);
    float4 o1 = make_float4(acc[4][bi],acc[5][bi],acc[6][bi],acc[7][bi]);
    *(float4*)(pp + b*LAT + lq*8)   = o0;
    *(float4*)(pp + b*LAT + lq*8+4) = o1;
  }
}

// ---------------- kernel 3a: coalesced partial reduce: 1256 -> 8 -------------
__global__ __launch_bounds__(256) void k_red1(
    const float* __restrict__ partial, float* __restrict__ partial2)
{
  int idx = blockIdx.x*256 + threadIdx.x;
  int g = blockIdx.y;
  float s = 0.f;
  for (int j=0;j<RED_J;j++)
    s += partial[(size_t)(g + RED_G*j)*(BN*LAT) + idx];
  partial2[(size_t)g*(BN*LAT) + idx] = s;
}

// ---------------- kernel 3b: 8 -> zT[l][b] + bias ----------------------------
__global__ __launch_bounds__(256) void k_red2(
    const float* __restrict__ partial2, const float* __restrict__ b_enc,
    float* __restrict__ zT)
{
  int idx = blockIdx.x*256 + threadIdx.x;
  float s = 0.f;
#pragma unroll
  for (int g=0; g<RED_G; g++) s += partial2[(size_t)g*(BN*LAT) + idx];
  int b = idx >> 7, l = idx & 127;
  zT[l*BN + b] = s + b_enc[l];
}

// ---------------- kernel 4: decoder  d[b][vc] = z[b]·W_dec[:,vc] + b_dec -----
// 512 thr = 8 waves; wave wv owns b = wv*8..+7 (z scalarizes to s_load);
// lane owns 4 vc. l-loop in groups of 4: issue 4 independent dwordx4 Wd
// loads (MLP=4), then 128 FMAs. duty/wave ~22% x 8 waves/SIMD -> VALU-bound.
__global__ __launch_bounds__(512, 8) void k_dec(
    const float* __restrict__ zT, const float* __restrict__ Wd,
    const float* __restrict__ b_dec, float* __restrict__ d)
{
  int t = threadIdx.x;
  int lane = t & 63;
  int wv = __builtin_amdgcn_readfirstlane(t >> 6);   // wave-uniform 0..7
  int vc = blockIdx.x*256 + lane*4;
  int vs = vc < (KTOT-4) ? vc : (KTOT-4);            // clamped load address
  const float* zrow = zT + wv*8;                     // + l*BN, wave-uniform
  float acc[4][8];
#pragma unroll
  for (int i=0;i<4;i++)
#pragma unroll
    for (int j=0;j<8;j++) acc[i][j]=0.f;
  for (int l0=0; l0<LAT; l0+=4){
    float4 w[4];
#pragma unroll
    for (int u=0;u<4;u++)
      w[u] = *(const float4*)(Wd + (size_t)(l0+u)*KTOT + vs);
#pragma unroll
    for (int u=0;u<4;u++){
      float zv[8];
#pragma unroll
      for (int j=0;j<8;j++) zv[j] = zrow[(l0+u)*BN + j];   // uniform -> s_load
      float wvv[4] = {w[u].x,w[u].y,w[u].z,w[u].w};
#pragma unroll
      for (int i=0;i<4;i++)
#pragma unroll
        for (int j=0;j<8;j++) acc[i][j] += wvv[i]*zv[j];
    }
  }
  if (vc < KTOT){
    float4 bd = *(const float4*)(b_dec + vc);
#pragma unroll
    for (int j=0;j<8;j++){
      int b = wv*8 + j;
      float4 o = make_float4(acc[0][j]+bd.x, acc[1][j]+bd.y,
                             acc[2][j]+bd.z, acc[3][j]+bd.w);
      *(float4*)(d + (size_t)b*KTOT + vc) = o;
    }
  }
}

// ---------------- kernel 5: per-vertex T[9] and G[27] precompute -------------
__global__ __launch_bounds__(256, 4) void k_tg(
    const float* __restrict__ d, const float* __restrict__ u_d,
    const float* __restrict__ W_d, float* __restrict__ TG)
{
  int t = blockIdx.x*256 + threadIdx.x;
  if (t >= NBV) return;
  const float* drow = d + (size_t)t*CH;
  float T[MN], G[27];
#pragma unroll
  for (int m=0;m<MN;m++) T[m]=0.f;
#pragma unroll
  for (int i=0;i<27;i++) G[i]=0.f;
  for (int c0=0;c0<CH;c0+=4){
    float4 dv = *(const float4*)(drow+c0);
    float dvv[4] = {dv.x,dv.y,dv.z,dv.w};
#pragma unroll
    for (int j=0;j<4;j++){
      int c = c0+j;
      float xv = dvv[j];
#pragma unroll
      for (int m=0;m<MN;m++) T[m] += xv*u_d[c*MN+m];
#pragma unroll
      for (int m=0;m<MN;m++){
        G[m*3+0] += xv*W_d[(m*CH+c)*3+0];
        G[m*3+1] += xv*W_d[(m*CH+c)*3+1];
        G[m*3+2] += xv*W_d[(m*CH+c)*3+2];
      }
    }
  }
  float* tg = TG + (size_t)t*36;
  float rr[36] = {T[0],T[1],T[2],T[3],T[4],T[5],T[6],T[7],T[8],
                  G[0],G[1],G[2],G[3],G[4],G[5],G[6],G[7],G[8],
                  G[9],G[10],G[11],G[12],G[13],G[14],G[15],G[16],G[17],
                  G[18],G[19],G[20],G[21],G[22],G[23],G[24],G[25],G[26]};
#pragma unroll
  for (int i=0;i<36;i+=4)
    *(float4*)(tg+i) = make_float4(rr[i],rr[i+1],rr[i+2],rr[i+3]);
}

// ---------------- kernel 6: attention + output -------------------------------
// XCD-chunked swizzle (1256 = 8*157, bijective) for TG L2 locality;
// 2-deep edge pipeline: issue edge k+1's 9 gathers before computing edge k.
__global__ __launch_bounds__(256, 4) void k_att(
    const float* __restrict__ TG, const float* __restrict__ aw,
    const int* __restrict__ dst, const float* __restrict__ c_d,
    const float* __restrict__ b_d, float* __restrict__ out)
{
  int wg = blockIdx.x;
  int wgid = (wg & 7)*157 + (wg >> 3);    // chunk per XCD
  int t = wgid*256 + threadIdx.x;
  if (t >= NBV) return;
  int b = t / VN, v = t - b*VN;
  const float* TGb = TG + (size_t)b*VN*36;
  int e0 = v*KN;
  int4 j01 = *(const int4*)(dst + e0);
  int4 j23 = *(const int4*)(dst + e0 + 4);
  int jj[8] = {j01.x,j01.y,j01.z,j01.w, j23.x,j23.y,j23.z,j23.w};
  float4 a01 = *(const float4*)(aw + e0);
  float4 a23 = *(const float4*)(aw + e0 + 4);
  float awv[8] = {a01.x,a01.y,a01.z,a01.w, a23.x,a23.y,a23.z,a23.w};
  float Ti[MN];
#pragma unroll
  for (int m=0;m<MN;m++) Ti[m] = TGb[(size_t)v*36+m] + c_d[m];
  float y0=0.f, y1=0.f, y2=0.f;
  float4 q[9];
  {
    const float* Rp = TGb + (size_t)jj[0]*36;
#pragma unroll
    for (int i=0;i<9;i++) q[i] = *(const float4*)(Rp + i*4);
  }
#pragma unroll
  for (int k=0;k<KN;k++){
    float4 p[9];
    if (k+1 < KN){
      const float* Rp = TGb + (size_t)jj[k+1]*36;
#pragma unroll
      for (int i=0;i<9;i++) p[i] = *(const float4*)(Rp + i*4);
    }
    float rr[36] = {q[0].x,q[0].y,q[0].z,q[0].w, q[1].x,q[1].y,q[1].z,q[1].w,
                    q[2].x,q[2].y,q[2].z,q[2].w, q[3].x,q[3].y,q[3].z,q[3].w,
                    q[4].x,q[4].y,q[4].z,q[4].w, q[5].x,q[5].y,q[5].z,q[5].w,
                    q[6].x,q[6].y,q[6].z,q[6].w, q[7].x,q[7].y,q[7].z,q[7].w,
                    q[8].x,q[8].y,q[8].z,q[8].w};
    float lg[MN];
#pragma unroll
    for (int m=0;m<MN;m++) lg[m] = Ti[m] - rr[m];
    float mx = lg[0];
#pragma unroll
    for (int m=1;m<MN;m++) mx = fmaxf(mx, lg[m]);
    float ex[MN], s=0.f;
#pragma unroll
    for (int m=0;m<MN;m++){ ex[m] = __expf(lg[m]-mx); s += ex[m]; }
    float sc = awv[k] / s;
#pragma unroll
    for (int m=0;m<MN;m++){
      float a = ex[m]*sc;
      y0 += a*rr[9+m*3+0]; y1 += a*rr[9+m*3+1]; y2 += a*rr[9+m*3+2];
    }
    if (k+1 < KN){
#pragma unroll
      for (int i=0;i<9;i++) q[i] = p[i];
    }
  }
  float* o = out + (size_t)t*3;
  o[0]=fmaxf(y0+b_d[0],0.f); o[1]=fmaxf(y1+b_d[1],0.f); o[2]=fmaxf(y2+b_d[2],0.f);
}

extern "C" void kernel_launch(void* const* d_in, const int* in_sizes, int n_in,
                              void* d_out, int out_size, void* d_ws, size_t ws_size,
                              hipStream_t stream) {
  const float* x     = (const float*)d_in[0];
  const float* aw    = (const float*)d_in[1];
  const float* u_e   = (const float*)d_in[2];
  const float* c_e   = (const float*)d_in[3];
  const float* W_e   = (const float*)d_in[4];
  const float* b_e   = (const float*)d_in[5];
  const float* W_enc = (const float*)d_in[6];
  const float* b_enc = (const float*)d_in[7];
  const float* W_dec = (const float*)d_in[8];
  const float* b_dec = (const float*)d_in[9];
  const float* u_d   = (const float*)d_in[10];
  const float* c_d   = (const float*)d_in[11];
  const float* W_d   = (const float*)d_in[12];
  const float* b_d   = (const float*)d_in[13];
  const int*   dst   = (const int*)d_in[15];
  float* out = (float*)d_out;

  char* ws = (char*)d_ws;
  float* hbuf = (float*)ws;                               // 82.3 MB (h, then d)
  size_t off1 = (size_t)NBV*CH*sizeof(float);
  float* partial = (float*)(ws + off1);                   // 41.2 MB
  float* TGbuf   = (float*)(ws + off1);                   // 46.3 MB (overlaps partial)
  size_t offz = off1 + (size_t)NCHUNK*(BN*LAT)*sizeof(float);
  float* zT       = (float*)(ws + offz);                  // 32 KB
  float* partial2 = (float*)(ws + offz + (size_t)(BN*LAT)*sizeof(float)); // 256 KB

  int grid_bv = (NBV + 255)/256;   // 1256

  k_conv1<<<grid_bv,256,0,stream>>>(x, aw, dst, u_e, c_e, W_e, b_e, hbuf);
  k_enc<<<NCHUNK,256,0,stream>>>(hbuf, W_enc, partial);
  dim3 gr1(32, RED_G);
  k_red1<<<gr1,256,0,stream>>>(partial, partial2);
  k_red2<<<32,256,0,stream>>>(partial2, b_enc, zT);
  int grid_dec = (KTOT + 255)/256;   // 1256 (last block: 192 valid vc)
  k_dec<<<grid_dec,512,0,stream>>>(zT, W_dec, b_dec, hbuf);   // d overwrites h
  k_tg<<<grid_bv,256,0,stream>>>(hbuf, u_d, W_d, TGbuf);
  k_att<<<grid_bv,256,0,stream>>>(TGbuf, aw, dst, c_d, b_d, out);
}

// Round 8
// 347.553 us; speedup vs baseline: 1.3988x; 1.0136x over previous
//
#include <hip/hip_runtime.h>

#define VN 5023
#define KN 8
#define BN 64
#define CIN 3
#define CH 64
#define MN 9
#define LAT 128
#define KTOT (VN*CH)      // 321472
#define NBV (BN*VN)       // 321472
#define KC 256
#define NCHUNK 1256       // ceil(KTOT/KC); last chunk has 192 = 6*32 valid k
#define RED_G 8
#define RED_J 157         // 1256 = 8*157 exactly
#define NXCD 8

// ---------------- kernel 1: conv1 (x[B,V,3] -> h[B,V,64], relu) --------------
__global__ __launch_bounds__(256, 4) void k_conv1(
    const float* __restrict__ x, const float* __restrict__ aw,
    const int* __restrict__ dst,
    const float* __restrict__ u_e, const float* __restrict__ c_e,
    const float* __restrict__ W_e, const float* __restrict__ b_e,
    float* __restrict__ h)
{
  int t = blockIdx.x*256 + threadIdx.x;
  if (t >= NBV) return;
  int b = t / VN, v = t - b*VN;
  const float* xb = x + (size_t)b*VN*CIN;
  float xi0 = xb[v*3+0], xi1 = xb[v*3+1], xi2 = xb[v*3+2];
  float Ti[MN];
#pragma unroll
  for (int m=0;m<MN;m++)
    Ti[m] = xi0*u_e[m] + xi1*u_e[MN+m] + xi2*u_e[2*MN+m] + c_e[m];
  float agg[27];
#pragma unroll
  for (int i=0;i<27;i++) agg[i]=0.f;
  for (int k=0;k<KN;k++){
    int e = v*KN+k;
    int j = dst[e];
    float awe = aw[e];
    float xj0 = xb[j*3+0], xj1 = xb[j*3+1], xj2 = xb[j*3+2];
    float lg[MN];
#pragma unroll
    for (int m=0;m<MN;m++)
      lg[m] = Ti[m] - (xj0*u_e[m]+xj1*u_e[MN+m]+xj2*u_e[2*MN+m]);
    float mx = lg[0];
#pragma unroll
    for (int m=1;m<MN;m++) mx = fmaxf(mx, lg[m]);
    float ex[MN], s=0.f;
#pragma unroll
    for (int m=0;m<MN;m++){ ex[m] = __expf(lg[m]-mx); s += ex[m]; }
    float r = awe / s;
#pragma unroll
    for (int m=0;m<MN;m++){
      float a = ex[m]*r;
      agg[m*3+0] += a*xj0; agg[m*3+1] += a*xj1; agg[m*3+2] += a*xj2;
    }
  }
  float* hr = h + (size_t)t*CH;
  for (int cc=0; cc<4; cc++){
    float y[16];
#pragma unroll
    for (int c=0;c<16;c++) y[c] = b_e[cc*16+c];
#pragma unroll
    for (int mc=0; mc<27; mc++){
      float a = agg[mc];
#pragma unroll
      for (int c=0;c<16;c++) y[c] += a * W_e[mc*CH + cc*16 + c];
    }
#pragma unroll
    for (int c=0;c<16;c+=4){
      float4 o = make_float4(fmaxf(y[c],0.f),fmaxf(y[c+1],0.f),
                             fmaxf(y[c+2],0.f),fmaxf(y[c+3],0.f));
      *(float4*)(hr + cc*16 + c) = o;
    }
  }
}

// ---------------- kernel 2: encoder split-K partials (pipelined) -------------
__global__ __launch_bounds__(256, 4) void k_enc(
    const float* __restrict__ h, const float* __restrict__ We,
    float* __restrict__ partial)
{
  __shared__ float wlds[2][32*128];   // 2 x 16 KB, [kk][l] linear
  __shared__ float hlds[2][32][68];   // 2 x 8.7 KB, [kk][b] padded
  int t = threadIdx.x;
  int blk = blockIdx.x;
  int lq = t & 15;
  int bq = t >> 4;
  float acc[8][4];
#pragma unroll
  for (int i=0;i<8;i++)
#pragma unroll
    for (int j=0;j<4;j++) acc[i][j]=0.f;
  int kbase0 = blk*KC;
  int ldb = t & 63;
  int seg = t >> 6;
  int nt0 = (blk == NCHUNK-1) ? 6 : 8;

  float4 wreg0, wreg1, wreg2, wreg3, hreg0, hreg1;
  {
    const float* wsrc = We + (size_t)kbase0*LAT;
    wreg0 = *(const float4*)(wsrc + 0*1024 + t*4);
    wreg1 = *(const float4*)(wsrc + 1*1024 + t*4);
    wreg2 = *(const float4*)(wsrc + 2*1024 + t*4);
    wreg3 = *(const float4*)(wsrc + 3*1024 + t*4);
    const float* hsrc = h + (size_t)ldb*KTOT + kbase0 + seg*8;
    hreg0 = *(const float4*)(hsrc);
    hreg1 = *(const float4*)(hsrc + 4);
    *(float4*)(&wlds[0][0*1024 + t*4]) = wreg0;
    *(float4*)(&wlds[0][1*1024 + t*4]) = wreg1;
    *(float4*)(&wlds[0][2*1024 + t*4]) = wreg2;
    *(float4*)(&wlds[0][3*1024 + t*4]) = wreg3;
    hlds[0][seg*8+0][ldb]=hreg0.x; hlds[0][seg*8+1][ldb]=hreg0.y;
    hlds[0][seg*8+2][ldb]=hreg0.z; hlds[0][seg*8+3][ldb]=hreg0.w;
    hlds[0][seg*8+4][ldb]=hreg1.x; hlds[0][seg*8+5][ldb]=hreg1.y;
    hlds[0][seg*8+6][ldb]=hreg1.z; hlds[0][seg*8+7][ldb]=hreg1.w;
  }
  __syncthreads();

  int cur = 0;
  for (int t0=0; t0<nt0; t0++){
    bool pf = (t0+1 < nt0);
    if (pf){
      int kbase = kbase0 + (t0+1)*32;
      const float* wsrc = We + (size_t)kbase*LAT;
      wreg0 = *(const float4*)(wsrc + 0*1024 + t*4);
      wreg1 = *(const float4*)(wsrc + 1*1024 + t*4);
      wreg2 = *(const float4*)(wsrc + 2*1024 + t*4);
      wreg3 = *(const float4*)(wsrc + 3*1024 + t*4);
      const float* hsrc = h + (size_t)ldb*KTOT + kbase + seg*8;
      hreg0 = *(const float4*)(hsrc);
      hreg1 = *(const float4*)(hsrc + 4);
    }
    __builtin_amdgcn_sched_barrier(0);
#pragma unroll 4
    for (int kk=0; kk<32; kk++){
      const float* wr = &wlds[cur][kk*128 + lq*8];
      float4 w0 = *(const float4*)wr;
      float4 w1 = *(const float4*)(wr+4);
      float4 z  = *(const float4*)(&hlds[cur][kk][bq*4]);
      float wv[8] = {w0.x,w0.y,w0.z,w0.w,w1.x,w1.y,w1.z,w1.w};
      float zv[4] = {z.x,z.y,z.z,z.w};
#pragma unroll
      for (int li=0;li<8;li++)
#pragma unroll
        for (int bi=0;bi<4;bi++) acc[li][bi] += wv[li]*zv[bi];
    }
    if (pf){
      int nb = cur^1;
      *(float4*)(&wlds[nb][0*1024 + t*4]) = wreg0;
      *(float4*)(&wlds[nb][1*1024 + t*4]) = wreg1;
      *(float4*)(&wlds[nb][2*1024 + t*4]) = wreg2;
      *(float4*)(&wlds[nb][3*1024 + t*4]) = wreg3;
      hlds[nb][seg*8+0][ldb]=hreg0.x; hlds[nb][seg*8+1][ldb]=hreg0.y;
      hlds[nb][seg*8+2][ldb]=hreg0.z; hlds[nb][seg*8+3][ldb]=hreg0.w;
      hlds[nb][seg*8+4][ldb]=hreg1.x; hlds[nb][seg*8+5][ldb]=hreg1.y;
      hlds[nb][seg*8+6][ldb]=hreg1.z; hlds[nb][seg*8+7][ldb]=hreg1.w;
    }
    __syncthreads();
    cur ^= 1;
  }
  float* pp = partial + (size_t)blk*(BN*LAT);
#pragma unroll
  for (int bi=0;bi<4;bi++){
    int b = bq*4+bi;
    float4 o0 = make_float4(acc[0][bi],acc[1][bi],acc[2][bi],acc[3][bi]);
    float4 o1 = make_float4(acc[4][bi],acc[5][bi],acc[6][bi],acc[7][bi]);
    *(float4*)(pp + b*LAT + lq*8)   = o0;
    *(float4*)(pp + b*LAT + lq*8+4) = o1;
  }
}

// ---------------- kernel 3a: coalesced partial reduce: 1256 -> 8 -------------
__global__ __launch_bounds__(256) void k_red1(
    const float* __restrict__ partial, float* __restrict__ partial2)
{
  int idx = blockIdx.x*256 + threadIdx.x;
  int g = blockIdx.y;
  float s = 0.f;
  for (int j=0;j<RED_J;j++)
    s += partial[(size_t)(g + RED_G*j)*(BN*LAT) + idx];
  partial2[(size_t)g*(BN*LAT) + idx] = s;
}

// ---------------- kernel 3b: 8 -> zT[l][b] + bias ----------------------------
__global__ __launch_bounds__(256) void k_red2(
    const float* __restrict__ partial2, const float* __restrict__ b_enc,
    float* __restrict__ zT)
{
  int idx = blockIdx.x*256 + threadIdx.x;
  float s = 0.f;
#pragma unroll
  for (int g=0; g<RED_G; g++) s += partial2[(size_t)g*(BN*LAT) + idx];
  int b = idx >> 7, l = idx & 127;
  zT[l*BN + b] = s + b_enc[l];
}

// ---------------- kernel 4: decoder  d[b][vc] = z[b]·W_dec[:,vc] + b_dec -----
// 512 thr = 8 waves, __launch_bounds__(512,4): 128-VGPR budget so the
// two-group (wA/wB, 4 float4 each) software pipeline keeps 4-8 loads in
// flight; sched_barrier(0) fences stop hipcc from sinking the prefetch.
// Wave wv owns b=wv*8..+7 (z scalarizes to s_load); lane owns 4 vc.
__global__ __launch_bounds__(512, 4) void k_dec(
    const float* __restrict__ zT, const float* __restrict__ Wd,
    const float* __restrict__ b_dec, float* __restrict__ d)
{
  int t = threadIdx.x;
  int lane = t & 63;
  int wv = __builtin_amdgcn_readfirstlane(t >> 6);   // wave-uniform 0..7
  int vc = blockIdx.x*256 + lane*4;
  int vs = vc < (KTOT-4) ? vc : (KTOT-4);            // clamped load address
  const float* wp = Wd + vs;
  const float* zrow = zT + wv*8;                     // wave-uniform
  float acc[4][8];
#pragma unroll
  for (int i=0;i<4;i++)
#pragma unroll
    for (int j=0;j<8;j++) acc[i][j]=0.f;

  float4 wA[4], wB[4];
#pragma unroll
  for (int u=0;u<4;u++) wA[u] = *(const float4*)(wp + (size_t)u*KTOT);

  for (int l0=0; l0<LAT; l0+=8){
    // prefetch group B (l0+4..l0+7)
#pragma unroll
    for (int u=0;u<4;u++) wB[u] = *(const float4*)(wp + (size_t)(l0+4+u)*KTOT);
    __builtin_amdgcn_sched_barrier(0);
    // compute group A (l0..l0+3)
#pragma unroll
    for (int u=0;u<4;u++){
      int l = l0+u;
      float zv[8];
#pragma unroll
      for (int j=0;j<8;j++) zv[j] = zrow[l*BN + j];    // uniform -> s_load
      float wvv[4] = {wA[u].x,wA[u].y,wA[u].z,wA[u].w};
#pragma unroll
      for (int i=0;i<4;i++)
#pragma unroll
        for (int j=0;j<8;j++) acc[i][j] += wvv[i]*zv[j];
    }
    // prefetch next group A (l0+8..l0+11)
    if (l0+8 < LAT){
#pragma unroll
      for (int u=0;u<4;u++) wA[u] = *(const float4*)(wp + (size_t)(l0+8+u)*KTOT);
    }
    __builtin_amdgcn_sched_barrier(0);
    // compute group B (l0+4..l0+7)
#pragma unroll
    for (int u=0;u<4;u++){
      int l = l0+4+u;
      float zv[8];
#pragma unroll
      for (int j=0;j<8;j++) zv[j] = zrow[l*BN + j];
      float wvv[4] = {wB[u].x,wB[u].y,wB[u].z,wB[u].w};
#pragma unroll
      for (int i=0;i<4;i++)
#pragma unroll
        for (int j=0;j<8;j++) acc[i][j] += wvv[i]*zv[j];
    }
  }
  if (vc < KTOT){
    float4 bd = *(const float4*)(b_dec + vc);
#pragma unroll
    for (int j=0;j<8;j++){
      int b = wv*8 + j;
      float4 o = make_float4(acc[0][j]+bd.x, acc[1][j]+bd.y,
                             acc[2][j]+bd.z, acc[3][j]+bd.w);
      *(float4*)(d + (size_t)b*KTOT + vc) = o;
    }
  }
}

// ---------------- kernel 5: per-vertex T[9] and G[27] precompute -------------
__global__ __launch_bounds__(256, 4) void k_tg(
    const float* __restrict__ d, const float* __restrict__ u_d,
    const float* __restrict__ W_d, float* __restrict__ TG)
{
  int t = blockIdx.x*256 + threadIdx.x;
  if (t >= NBV) return;
  const float* drow = d + (size_t)t*CH;
  float T[MN], G[27];
#pragma unroll
  for (int m=0;m<MN;m++) T[m]=0.f;
#pragma unroll
  for (int i=0;i<27;i++) G[i]=0.f;
  for (int c0=0;c0<CH;c0+=4){
    float4 dv = *(const float4*)(drow+c0);
    float dvv[4] = {dv.x,dv.y,dv.z,dv.w};
#pragma unroll
    for (int j=0;j<4;j++){
      int c = c0+j;
      float xv = dvv[j];
#pragma unroll
      for (int m=0;m<MN;m++) T[m] += xv*u_d[c*MN+m];
#pragma unroll
      for (int m=0;m<MN;m++){
        G[m*3+0] += xv*W_d[(m*CH+c)*3+0];
        G[m*3+1] += xv*W_d[(m*CH+c)*3+1];
        G[m*3+2] += xv*W_d[(m*CH+c)*3+2];
      }
    }
  }
  float* tg = TG + (size_t)t*36;
  float rr[36] = {T[0],T[1],T[2],T[3],T[4],T[5],T[6],T[7],T[8],
                  G[0],G[1],G[2],G[3],G[4],G[5],G[6],G[7],G[8],
                  G[9],G[10],G[11],G[12],G[13],G[14],G[15],G[16],G[17],
                  G[18],G[19],G[20],G[21],G[22],G[23],G[24],G[25],G[26]};
#pragma unroll
  for (int i=0;i<36;i+=4)
    *(float4*)(tg+i) = make_float4(rr[i],rr[i+1],rr[i+2],rr[i+3]);
}

// ---------------- kernel 6: attention + output -------------------------------
__global__ __launch_bounds__(256, 4) void k_att(
    const float* __restrict__ TG, const float* __restrict__ aw,
    const int* __restrict__ dst, const float* __restrict__ c_d,
    const float* __restrict__ b_d, float* __restrict__ out)
{
  int wg = blockIdx.x;
  int wgid = (wg & 7)*157 + (wg >> 3);    // chunk per XCD
  int t = wgid*256 + threadIdx.x;
  if (t >= NBV) return;
  int b = t / VN, v = t - b*VN;
  const float* TGb = TG + (size_t)b*VN*36;
  int e0 = v*KN;
  int4 j01 = *(const int4*)(dst + e0);
  int4 j23 = *(const int4*)(dst + e0 + 4);
  int jj[8] = {j01.x,j01.y,j01.z,j01.w, j23.x,j23.y,j23.z,j23.w};
  float4 a01 = *(const float4*)(aw + e0);
  float4 a23 = *(const float4*)(aw + e0 + 4);
  float awv[8] = {a01.x,a01.y,a01.z,a01.w, a23.x,a23.y,a23.z,a23.w};
  float Ti[MN];
#pragma unroll
  for (int m=0;m<MN;m++) Ti[m] = TGb[(size_t)v*36+m] + c_d[m];
  float y0=0.f, y1=0.f, y2=0.f;
  float4 q[9];
  {
    const float* Rp = TGb + (size_t)jj[0]*36;
#pragma unroll
    for (int i=0;i<9;i++) q[i] = *(const float4*)(Rp + i*4);
  }
#pragma unroll
  for (int k=0;k<KN;k++){
    float4 p[9];
    if (k+1 < KN){
      const float* Rp = TGb + (size_t)jj[k+1]*36;
#pragma unroll
      for (int i=0;i<9;i++) p[i] = *(const float4*)(Rp + i*4);
    }
    float rr[36] = {q[0].x,q[0].y,q[0].z,q[0].w, q[1].x,q[1].y,q[1].z,q[1].w,
                    q[2].x,q[2].y,q[2].z,q[2].w, q[3].x,q[3].y,q[3].z,q[3].w,
                    q[4].x,q[4].y,q[4].z,q[4].w, q[5].x,q[5].y,q[5].z,q[5].w,
                    q[6].x,q[6].y,q[6].z,q[6].w, q[7].x,q[7].y,q[7].z,q[7].w,
                    q[8].x,q[8].y,q[8].z,q[8].w};
    float lg[MN];
#pragma unroll
    for (int m=0;m<MN;m++) lg[m] = Ti[m] - rr[m];
    float mx = lg[0];
#pragma unroll
    for (int m=1;m<MN;m++) mx = fmaxf(mx, lg[m]);
    float ex[MN], s=0.f;
#pragma unroll
    for (int m=0;m<MN;m++){ ex[m] = __expf(lg[m]-mx); s += ex[m]; }
    float sc = awv[k] / s;
#pragma unroll
    for (int m=0;m<MN;m++){
      float a = ex[m]*sc;
      y0 += a*rr[9+m*3+0]; y1 += a*rr[9+m*3+1]; y2 += a*rr[9+m*3+2];
    }
    if (k+1 < KN){
#pragma unroll
      for (int i=0;i<9;i++) q[i] = p[i];
    }
  }
  float* o = out + (size_t)t*3;
  o[0]=fmaxf(y0+b_d[0],0.f); o[1]=fmaxf(y1+b_d[1],0.f); o[2]=fmaxf(y2+b_d[2],0.f);
}

extern "C" void kernel_launch(void* const* d_in, const int* in_sizes, int n_in,
                              void* d_out, int out_size, void* d_ws, size_t ws_size,
                              hipStream_t stream) {
  const float* x     = (const float*)d_in[0];
  const float* aw    = (const float*)d_in[1];
  const float* u_e   = (const float*)d_in[2];
  const float* c_e   = (const float*)d_in[3];
  const float* W_e   = (const float*)d_in[4];
  const float* b_e   = (const float*)d_in[5];
  const float* W_enc = (const float*)d_in[6];
  const float* b_enc = (const float*)d_in[7];
  const float* W_dec = (const float*)d_in[8];
  const float* b_dec = (const float*)d_in[9];
  const float* u_d   = (const float*)d_in[10];
  const float* c_d   = (const float*)d_in[11];
  const float* W_d   = (const float*)d_in[12];
  const float* b_d   = (const float*)d_in[13];
  const int*   dst   = (const int*)d_in[15];
  float* out = (float*)d_out;

  char* ws = (char*)d_ws;
  float* hbuf = (float*)ws;                               // 82.3 MB (h, then d)
  size_t off1 = (size_t)NBV*CH*sizeof(float);
  float* partial = (float*)(ws + off1);                   // 41.2 MB
  float* TGbuf   = (float*)(ws + off1);                   // 46.3 MB (overlaps partial)
  size_t offz = off1 + (size_t)NCHUNK*(BN*LAT)*sizeof(float);
  float* zT       = (float*)(ws + offz);                  // 32 KB
  float* partial2 = (float*)(ws + offz + (size_t)(BN*LAT)*sizeof(float)); // 256 KB

  int grid_bv = (NBV + 255)/256;   // 1256

  k_conv1<<<grid_bv,256,0,stream>>>(x, aw, dst, u_e, c_e, W_e, b_e, hbuf);
  k_enc<<<NCHUNK,256,0,stream>>>(hbuf, W_enc, partial);
  dim3 gr1(32, RED_G);
  k_red1<<<gr1,256,0,stream>>>(partial, partial2);
  k_red2<<<32,256,0,stream>>>(partial2, b_enc, zT);
  int grid_dec = (KTOT + 255)/256;   // 1256 (last block: 192 valid vc)
  k_dec<<<grid_dec,512,0,stream>>>(zT, W_dec, b_dec, hbuf);   // d overwrites h
  k_tg<<<grid_bv,256,0,stream>>>(hbuf, u_d, W_d, TGbuf);
  k_att<<<grid_bv,256,0,stream>>>(TGbuf, aw, dst, c_d, b_d, out);
}